// Round 7
// baseline (986.066 us; speedup 1.0000x reference)
//
#include <hip/hip_runtime.h>
#include <cstddef>
#include <cstdint>

typedef short short8 __attribute__((ext_vector_type(8)));
typedef unsigned short ushort8v __attribute__((ext_vector_type(8)));
typedef float float16 __attribute__((ext_vector_type(16)));
typedef unsigned short ushort;

namespace {

constexpr int H = 128;

__device__ inline ushort f2bf(float v) {
    unsigned u = __float_as_uint(v);
    unsigned r = u + 0x7fffu + ((u >> 16) & 1u);
    return (ushort)(r >> 16);
}
__device__ inline float bf2f(ushort b) { return __uint_as_float((unsigned)b << 16); }
__device__ inline float blo(unsigned v) { return __uint_as_float(v << 16); }
__device__ inline float bhiF(unsigned v) { return __uint_as_float(v & 0xffff0000u); }

// ---------------- edge-index dtype detection ----------------
__global__ void detect_kernel(const int* __restrict__ ei, int* __restrict__ flag) {
    __shared__ int cnt;
    if (threadIdx.x == 0) cnt = 0;
    __syncthreads();
    int z = 0;
    for (int i = threadIdx.x; i < 2048; i += 256)
        if (ei[2 * i + 1] == 0) z++;
    atomicAdd(&cnt, z);
    __syncthreads();
    if (threadIdx.x == 0) *flag = (cnt > 1024) ? 1 : 0;
}

// ---------------- one-pass: convert + in-degree + CSR fill (ushort, 32+32 spill) ----------------
__global__ void build_kernel(const int* __restrict__ ei, const int* __restrict__ flag,
                             int* __restrict__ degi, int* __restrict__ cnt,
                             ushort* __restrict__ csr, ushort* __restrict__ csr2, int E) {
    int e = blockIdx.x * 256 + threadIdx.x;
    if (e >= E) return;
    int r, c;
    if (*flag) { r = ei[2 * e]; c = ei[2 * (E + e)]; }
    else       { r = ei[e];     c = ei[E + e]; }
    if (r == c) return;
    atomicAdd(&degi[c], 1);
    int slot = atomicAdd(&cnt[r], 1);
    if (slot < 32)      csr [((size_t)r << 5) + slot]      = (ushort)c;
    else if (slot < 64) csr2[((size_t)r << 5) + slot - 32] = (ushort)c;
}

__global__ void dinv_kernel(const int* __restrict__ degi, float* __restrict__ d, int n) {
    int i = blockIdx.x * 256 + threadIdx.x;
    if (i < n) d[i] = rsqrtf(1.0f + (float)degi[i]);
}

// ---------------- panel SpMM: out[r,p] = bf16( dinv[r] * (z[r,p] + sum_nbr z[c,p]) ) ----------------
// z and out are PANEL-MAJOR: [panel][node][16 features] (32 B/node/panel, 1.6 MB/panel).
// panel = blockIdx % 8 -> one XCD per panel (L2-resident gathers). 8 lanes/edge, 8 edges/instr,
// 2 rows per wave for MLP, butterfly reduce over lane-groups.
__global__ __launch_bounds__(256)
void spmm_kernel(const int* __restrict__ cnt, const ushort* __restrict__ csr,
                 const ushort* __restrict__ csr2, const float* __restrict__ dinv,
                 const ushort* __restrict__ z, ushort* __restrict__ outp, int n) {
    const int panel = blockIdx.x & 7;
    const int pb = blockIdx.x >> 3;
    const int wave = threadIdx.x >> 6;
    const int lane = threadIdx.x & 63;
    const int g = lane >> 3, f = lane & 7;
    const size_t pstr = (size_t)n << 4;          // ushorts per panel
    const ushort* zp = z + panel * pstr;
    ushort* op = outp + panel * pstr;
    const int row0 = (pb * 4 + wave) * 2;
    if (row0 >= n) return;
    const int row1 = row0 + 1;
    const bool has1 = row1 < n;
    int dr0 = cnt[row0]; if (dr0 > 64) dr0 = 64;
    int dr1 = has1 ? cnt[row1] : 0; if (dr1 > 64) dr1 = 64;
    const int d0 = dr0 > 32 ? 32 : dr0;
    const int d1 = dr1 > 32 ? 32 : dr1;
    const ushort* c0 = csr + ((size_t)row0 << 5);
    const ushort* c1 = csr + ((size_t)row1 << 5);
    float ax0 = 0.f, ay0 = 0.f, ax1 = 0.f, ay1 = 0.f;
    const int dmax = d0 > d1 ? d0 : d1;
    for (int j0 = 0; j0 < dmax; j0 += 8) {
        int jj = j0 + g;
        int cA = (jj < d0) ? (int)c0[jj] : row0;
        float sA = (jj < d0) ? 1.f : 0.f;
        int cB = (jj < d1) ? (int)c1[jj] : row1;
        float sB = (jj < d1) ? 1.f : 0.f;
        unsigned vA = *(const unsigned*)(zp + ((size_t)cA << 4) + (f << 1));
        unsigned vB = *(const unsigned*)(zp + ((size_t)cB << 4) + (f << 1));
        ax0 = fmaf(sA, blo(vA), ax0); ay0 = fmaf(sA, bhiF(vA), ay0);
        ax1 = fmaf(sB, blo(vB), ax1); ay1 = fmaf(sB, bhiF(vB), ay1);
    }
    if (dr0 > 32) {   // rare (P ~ 2e-5)
        const ushort* e0 = csr2 + ((size_t)row0 << 5);
        for (int j0 = 32; j0 < dr0; j0 += 8) {
            int jj = j0 + g;
            int cA = (jj < dr0) ? (int)e0[jj - 32] : row0;
            float sA = (jj < dr0) ? 1.f : 0.f;
            unsigned vA = *(const unsigned*)(zp + ((size_t)cA << 4) + (f << 1));
            ax0 = fmaf(sA, blo(vA), ax0); ay0 = fmaf(sA, bhiF(vA), ay0);
        }
    }
    if (dr1 > 32) {
        const ushort* e1 = csr2 + ((size_t)row1 << 5);
        for (int j0 = 32; j0 < dr1; j0 += 8) {
            int jj = j0 + g;
            int cB = (jj < dr1) ? (int)e1[jj - 32] : row1;
            float sB = (jj < dr1) ? 1.f : 0.f;
            unsigned vB = *(const unsigned*)(zp + ((size_t)cB << 4) + (f << 1));
            ax1 = fmaf(sB, blo(vB), ax1); ay1 = fmaf(sB, bhiF(vB), ay1);
        }
    }
#pragma unroll
    for (int dsh = 8; dsh < 64; dsh <<= 1) {
        ax0 += __shfl_xor(ax0, dsh, 64);
        ay0 += __shfl_xor(ay0, dsh, 64);
        ax1 += __shfl_xor(ax1, dsh, 64);
        ay1 += __shfl_xor(ay1, dsh, 64);
    }
    if (g == 0) {
        unsigned sv = *(const unsigned*)(zp + ((size_t)row0 << 4) + (f << 1));
        float di = dinv[row0];
        unsigned lo16 = f2bf(di * (ax0 + blo(sv)));
        unsigned hi16 = f2bf(di * (ay0 + bhiF(sv)));
        *(unsigned*)(op + ((size_t)row0 << 4) + (f << 1)) = lo16 | (hi16 << 16);
    } else if (g == 1 && has1) {
        unsigned sv = *(const unsigned*)(zp + ((size_t)row1 << 4) + (f << 1));
        float di = dinv[row1];
        unsigned lo16 = f2bf(di * (ax1 + blo(sv)));
        unsigned hi16 = f2bf(di * (ay1 + bhiF(sv)));
        *(unsigned*)(op + ((size_t)row1 << 4) + (f << 1)) = lo16 | (hi16 << 16);
    }
}

// ---------------- weight prep: split fp32 W[K][128] -> bf16 hi/lo, transposed [n][K] ----------------
__global__ void wprep_in_kernel(const float* __restrict__ W, ushort* __restrict__ hi,
                                ushort* __restrict__ lo) {   // K=64
    int i = blockIdx.x * 256 + threadIdx.x;   // < 64*128
    int k = i >> 7, nn = i & 127;
    float v = W[i];
    ushort h = f2bf(v);
    ushort l = f2bf(v - bf2f(h));
    size_t o = ((size_t)nn << 6) + k;
    hi[o] = h; lo[o] = l;
}

// 8 K=128 matrices: Wf[0..2], Wa[0..2], Wo1, Wo2 -> contiguous [mat][n][K]
__global__ void wprep8_kernel(const float* __restrict__ Wf, const float* __restrict__ Wa,
                              const float* __restrict__ Wo1, const float* __restrict__ Wo2,
                              ushort* __restrict__ hi, ushort* __restrict__ lo) {
    int i = blockIdx.x * 256 + threadIdx.x;   // < 8*16384
    int mat = i >> 14;
    int rem = i & 16383;
    int k = rem >> 7, nn = rem & 127;
    const float* src = (mat < 3) ? Wf + mat * 16384
                     : (mat < 6) ? Wa + (mat - 3) * 16384
                     : (mat == 6) ? Wo1 : Wo2;
    float v = src[rem];
    ushort h = f2bf(v);
    ushort l = f2bf(v - bf2f(h));
    size_t o = ((size_t)mat << 14) + ((size_t)nn << 7) + k;
    hi[o] = h; lo[o] = l;
}

// ---------------- single-barrier MFMA GEMM: (n x K) @ (K x 128) ----------------
// B (hi/lo) staged to LDS ONCE with XOR-swizzled 16B groups. A preloaded to registers.
// ABF=0: A fp32 row-major, split hi/lo (3 MFMAs/frag). ABF=1: A bf16 PANEL-MAJOR (2 MFMAs/frag).
// PRO=1: A' = relu(a*scale+shift), scale/shift finalized in-block from fsum/fsq + g/bt.
// EPI: 0=+bias, 1=sigmoid, 2=*y0^2, 3=*y0. STATS: col sum/sumsq -> ssum/ssq.
// WBF: write ybf = bf16(dinv[r]*v) PANEL-MAJOR. NOC: skip fp32 C write.
template <int K, int PRO, int EPI, int STATS, int WBF, int ABF, int NOC>
__global__ __launch_bounds__(256)
void mgemm_kernel(const void* __restrict__ Araw,
                  const ushort* __restrict__ Bhi, const ushort* __restrict__ Blo,
                  const float* __restrict__ bias,
                  const float* __restrict__ g, const float* __restrict__ bt,
                  const float* __restrict__ fsum, const float* __restrict__ fsq, float invn,
                  const float* __restrict__ y0, const float* __restrict__ dinv,
                  float* __restrict__ C, ushort* __restrict__ ybf,
                  float* __restrict__ ssum, float* __restrict__ ssq, int n) {
    constexpr int NG = K / 8;     // 16B groups per B row
    constexpr int GM = NG - 1;    // XOR swizzle mask
    constexpr int NCH = K / 16;   // MFMA K-chunks
    __shared__ __align__(16) ushort lds[2 * 128 * K];   // Bh | Bl (aliased by stats later)
    __shared__ float scs[128], shs[128];
    ushort* Bh = lds;
    ushort* Bl = lds + 128 * K;
    const int tid = threadIdx.x;
    const int lane = tid & 63;
    const int w = tid >> 6;
    const int m = lane & 31;
    const int half = lane >> 5;
    const int rowbase = blockIdx.x * 128;
    const int grow = rowbase + w * 32 + m;
    const bool rok = grow < n;
    const size_t pstr = (size_t)n << 4;   // panel stride in ushorts

    if (PRO == 1 && tid < K) {
        float mn = fsum[tid] * invn;
        float var = fmaxf(fsq[tid] * invn - mn * mn, 0.0f);
        float sc = g[tid] * rsqrtf(var + 1e-5f);
        scs[tid] = sc;
        shs[tid] = bt[tid] - mn * sc;
    }

    // --- stage all of B (hi/lo), swizzled ---
    for (int gi = tid; gi < 128 * NG; gi += 256) {
        int nn = gi / NG;
        int gg = gi & GM;
        int dst = nn * K + ((gg ^ (nn & GM)) << 3);
        *(ushort8v*)&Bh[dst] = *(const ushort8v*)(Bhi + (size_t)nn * K + (gg << 3));
        *(ushort8v*)&Bl[dst] = *(const ushort8v*)(Blo + (size_t)nn * K + (gg << 3));
    }

    // --- preload A for the whole K ---
    float4 aR[2 * NCH];
    short8 aB[NCH];
    if (ABF) {
        const ushort* Ab = (const ushort*)Araw + ((size_t)grow << 4) + half * 8;
#pragma unroll
        for (int ch = 0; ch < NCH; ++ch)
            aB[ch] = rok ? *(const short8*)(Ab + ch * pstr) : (short8)(short)0;
    } else {
        const float* A = (const float*)Araw + (size_t)grow * K + half * 8;
#pragma unroll
        for (int ch = 0; ch < NCH; ++ch) {
            aR[2 * ch]     = rok ? *(const float4*)(A + ch * 16)     : make_float4(0.f, 0.f, 0.f, 0.f);
            aR[2 * ch + 1] = rok ? *(const float4*)(A + ch * 16 + 4) : make_float4(0.f, 0.f, 0.f, 0.f);
        }
    }

    __syncthreads();   // the only barrier before the epilogue

    float16 acc[4];
#pragma unroll
    for (int t = 0; t < 4; ++t) acc[t] = (float16)(0.0f);

#pragma unroll
    for (int ch = 0; ch < NCH; ++ch) {
        short8 ah, al;
        if (ABF) {
            ah = aB[ch];
        } else {
            float av[8] = {aR[2 * ch].x,     aR[2 * ch].y,     aR[2 * ch].z,     aR[2 * ch].w,
                           aR[2 * ch + 1].x, aR[2 * ch + 1].y, aR[2 * ch + 1].z, aR[2 * ch + 1].w};
            if (PRO == 1) {
                const int kb = ch * 16 + half * 8;
#pragma unroll
                for (int q = 0; q < 8; ++q)
                    av[q] = fmaxf(fmaf(av[q], scs[kb + q], shs[kb + q]), 0.f);
            }
#pragma unroll
            for (int q = 0; q < 8; ++q) {
                ushort h = f2bf(av[q]);
                ah[q] = (short)h;
                al[q] = (short)f2bf(av[q] - bf2f(h));
            }
        }
        const int gg = 2 * ch + half;
#pragma unroll
        for (int t = 0; t < 4; ++t) {
            const int nn = t * 32 + m;
            const int bo = nn * K + ((gg ^ (nn & GM)) << 3);
            short8 bh = *(const short8*)&Bh[bo];
            short8 bl = *(const short8*)&Bl[bo];
            acc[t] = __builtin_amdgcn_mfma_f32_32x32x16_bf16(ah, bh, acc[t], 0, 0, 0);
            acc[t] = __builtin_amdgcn_mfma_f32_32x32x16_bf16(ah, bl, acc[t], 0, 0, 0);
            if (!ABF)
                acc[t] = __builtin_amdgcn_mfma_f32_32x32x16_bf16(al, bh, acc[t], 0, 0, 0);
        }
    }

    // --- epilogue ---
    float lsum[4], lsq[4];
    if (STATS) {
#pragma unroll
        for (int t = 0; t < 4; ++t) { lsum[t] = 0.f; lsq[t] = 0.f; }
    }
#pragma unroll
    for (int t = 0; t < 4; ++t) {
        const int col = t * 32 + m;
        const float bv = bias ? bias[col] : 0.0f;
        const size_t wboff = WBF ? ((size_t)(col >> 4) * pstr + (col & 15)) : 0;
#pragma unroll
        for (int r = 0; r < 16; ++r) {
            int rowl = w * 32 + (r & 3) + 8 * (r >> 2) + 4 * half;
            int gr = rowbase + rowl;
            if (gr < n) {
                float v = acc[t][r] + bv;
                if (EPI == 1) v = 1.0f / (1.0f + __expf(-v));
                if (EPI == 2 || EPI == 3) {
                    float t0 = y0[(size_t)gr * H + col];
                    v *= (EPI == 2) ? t0 * t0 : t0;
                }
                if (!NOC) C[(size_t)gr * H + col] = v;
                if (WBF) ybf[wboff + ((size_t)gr << 4)] = f2bf(dinv[gr] * v);
                if (STATS) { lsum[t] += v; lsq[t] += v * v; }
            }
        }
    }
    if (STATS) {
        __syncthreads();   // all B-reads done -> safe to alias LDS
        float* csum = (float*)lds;
        float* csq = csum + 128;
        if (tid < 128) { csum[tid] = 0.f; csq[tid] = 0.f; }
        __syncthreads();
#pragma unroll
        for (int t = 0; t < 4; ++t) {
            atomicAdd(&csum[t * 32 + m], lsum[t]);
            atomicAdd(&csq[t * 32 + m], lsq[t]);
        }
        __syncthreads();
        if (tid < 128) {
            atomicAdd(&ssum[tid], csum[tid]);
            atomicAdd(&ssq[tid], csq[tid]);
        }
    }
}

// ---------------- batchnorm apply (in-block finalize) + relu + residual ----------------
__global__ void bn_relu_res_kernel(float* __restrict__ io, const float* __restrict__ res,
                                   const float* __restrict__ fsum, const float* __restrict__ fsq,
                                   const float* __restrict__ g, const float* __restrict__ bt,
                                   float invn, int total4) {
    __shared__ float scs[128], shs[128];
    int tid = threadIdx.x;
    if (tid < 128) {
        float mn = fsum[tid] * invn;
        float var = fmaxf(fsq[tid] * invn - mn * mn, 0.0f);
        float sc = g[tid] * rsqrtf(var + 1e-5f);
        scs[tid] = sc;
        shs[tid] = bt[tid] - mn * sc;
    }
    __syncthreads();
    int i = blockIdx.x * 256 + tid;
    if (i >= total4) return;
    float4 v = ((float4*)io)[i];
    int c = (i << 2) & 127;
    v.x = fmaxf(fmaf(v.x, scs[c],     shs[c]),     0.f);
    v.y = fmaxf(fmaf(v.y, scs[c + 1], shs[c + 1]), 0.f);
    v.z = fmaxf(fmaf(v.z, scs[c + 2], shs[c + 2]), 0.f);
    v.w = fmaxf(fmaf(v.w, scs[c + 3], shs[c + 3]), 0.f);
    if (res) {
        float4 r = ((const float4*)res)[i];
        v.x += r.x; v.y += r.y; v.z += r.z; v.w += r.w;
    }
    ((float4*)io)[i] = v;
}

} // namespace

extern "C" void kernel_launch(void* const* d_in, const int* in_sizes, int n_in,
                              void* d_out, int out_size, void* d_ws, size_t ws_size,
                              hipStream_t stream) {
    const float* x     = (const float*)d_in[0];
    const int*   ei    = (const int*)d_in[1];
    const float* W_in  = (const float*)d_in[2];
    const float* b_in  = (const float*)d_in[3];
    const float* g_in  = (const float*)d_in[4];
    const float* bt_in = (const float*)d_in[5];
    const float* Wf    = (const float*)d_in[6];
    const float* Wa    = (const float*)d_in[7];
    const float* g_nm  = (const float*)d_in[8];
    const float* bt_nm = (const float*)d_in[9];
    const float* W_o1  = (const float*)d_in[10];
    const float* b_o1  = (const float*)d_in[11];
    const float* g_o   = (const float*)d_in[12];
    const float* bt_o  = (const float*)d_in[13];
    const float* W_o2  = (const float*)d_in[14];
    const float* b_o2  = (const float*)d_in[15];
    float* out = (float*)d_out;

    const int N = in_sizes[0] / 64;
    const int E = in_sizes[1] / 2;

    char* wsp = (char*)d_ws;
    size_t off = 0;
    auto alloc = [&](size_t bytes) -> void* {
        void* p = wsp + off;
        off = (off + bytes + 255) & ~(size_t)255;
        return p;
    };
    int*    flag  = (int*)   alloc(4);
    float*  stats = (float*) alloc(4096);                // 4 slices of (ssum128|ssq128)
    ushort* win_h = (ushort*)alloc(64 * H * 2);
    ushort* win_l = (ushort*)alloc(64 * H * 2);
    ushort* w8_h  = (ushort*)alloc(8 * H * H * 2);
    ushort* w8_l  = (ushort*)alloc(8 * H * H * 2);
    int*    cnts  = (int*)   alloc((size_t)2 * N * 4);   // degi | cnt (one memset)
    int*    degi  = cnts;
    int*    cnt   = cnts + N;
    float*  dinv  = (float*) alloc((size_t)N * 4);
    ushort* csr   = (ushort*)alloc((size_t)N * 32 * 2);  // main table (deg<=32)
    ushort* csr2  = (ushort*)alloc((size_t)N * 32 * 2);  // spill (32<deg<=64)
    ushort* zb    = (ushort*)alloc((size_t)N * H * 2);   // panel-major z (dinv-scaled)
    ushort* tz    = (ushort*)alloc((size_t)N * H * 2);   // panel-major spmm output
    float*  b0    = (float*) alloc((size_t)N * H * 4);
    float*  b1    = (float*) alloc((size_t)N * H * 4);
    float*  b3    = (float*) alloc((size_t)N * H * 4);

    float* s0 = stats;
    float* s1 = stats + 256;
    float* s2 = stats + 512;
    float* s3 = stats + 768;

    const int TB = 256;
    const int gE = (E + TB - 1) / TB;
    const int gN = (N + TB - 1) / TB;
    const int gG = (N + 127) / 128;
    const int pairs = (N + 1) / 2;
    const int gS = ((pairs + 3) / 4) * 8;   // 4 row-pairs per block, x8 panels
    const int gV = (N * H / 4 + TB - 1) / TB;
    const float invn = 1.0f / (float)N;
    const size_t HH = (size_t)H * H;

    // --- graph preprocessing: one pass ---
    detect_kernel<<<1, TB, 0, stream>>>(ei, flag);
    hipMemsetAsync(cnts, 0, (size_t)2 * N * 4, stream);
    hipMemsetAsync(stats, 0, 4096, stream);
    build_kernel<<<gE, TB, 0, stream>>>(ei, flag, degi, cnt, csr, csr2, E);
    dinv_kernel<<<gN, TB, 0, stream>>>(degi, dinv, N);

    // --- weight split prep ---
    wprep_in_kernel<<<(64 * H) / 256, TB, 0, stream>>>(W_in, win_h, win_l);
    wprep8_kernel<<<(8 * H * H) / 256, TB, 0, stream>>>(Wf, Wa, W_o1, W_o2, w8_h, w8_l);

    // --- input encoder: h = relu(BN(x @ W_in + b_in)) -> b0 ---
    mgemm_kernel<64, 0, 0, 1, 0, 0, 0><<<gG, TB, 0, stream>>>(x, win_h, win_l, b_in,
        nullptr, nullptr, nullptr, nullptr, 0.f, nullptr, nullptr,
        b0, nullptr, s0, s0 + 128, N);
    bn_relu_res_kernel<<<gV, TB, 0, stream>>>(b0, nullptr, s0, s0 + 128, g_in, bt_in,
                                              invn, N * H / 4);

    // --- RWKP conv layers ---
    float* hb = b0;
    float* fb = b3;
    float* slayer[2] = {s1, s2};
    for (int l = 0; l < 3; ++l) {
        const ushort* wfh = w8_h + (size_t)l * HH;
        const ushort* wfl = w8_l + (size_t)l * HH;
        const ushort* wah = w8_h + (size_t)(3 + l) * HH;
        const ushort* wal = w8_l + (size_t)(3 + l) * HH;
        // y0 = sigmoid(h @ Wf_l) -> b1 (fp32) + zb (bf16 panel-major, dinv-scaled)
        mgemm_kernel<128, 0, 1, 0, 1, 0, 0><<<gG, TB, 0, stream>>>(hb, wfh, wfl, nullptr,
            nullptr, nullptr, nullptr, nullptr, 0.f, nullptr, dinv,
            b1, zb, nullptr, nullptr, N);
        // t = A*y0 -> tz (bf16 panel-major)
        spmm_kernel<<<gS, TB, 0, stream>>>(cnt, csr, csr2, dinv, zb, tz, N);
        // y1 = y0^2 * (t @ Wa_l) -> zb only (bf16 panel-major, dinv-scaled)
        mgemm_kernel<128, 0, 2, 0, 1, 1, 1><<<gG, TB, 0, stream>>>(tz, wah, wal, nullptr,
            nullptr, nullptr, nullptr, nullptr, 0.f, b1, dinv,
            nullptr, zb, nullptr, nullptr, N);
        // t = A*y1 -> tz (bf16 panel-major)
        spmm_kernel<<<gS, TB, 0, stream>>>(cnt, csr, csr2, dinv, zb, tz, N);
        // hc = y0 * (t @ Wa_l) -> fb (fp32)
        if (l < 2) {
            float* sl = slayer[l];
            mgemm_kernel<128, 0, 3, 1, 0, 1, 0><<<gG, TB, 0, stream>>>(tz, wah, wal, nullptr,
                nullptr, nullptr, nullptr, nullptr, 0.f, b1, nullptr,
                fb, nullptr, sl, sl + 128, N);
            bn_relu_res_kernel<<<gV, TB, 0, stream>>>(fb, hb, sl, sl + 128,
                g_nm + l * H, bt_nm + l * H, invn, N * H / 4);
            float* t = hb; hb = fb; fb = t;
        } else {
            mgemm_kernel<128, 0, 3, 0, 0, 1, 0><<<gG, TB, 0, stream>>>(tz, wah, wal, nullptr,
                nullptr, nullptr, nullptr, nullptr, 0.f, b1, nullptr,
                fb, nullptr, nullptr, nullptr, N);
            hb = fb;
        }
    }

    // --- output encoder ---
    mgemm_kernel<128, 0, 0, 1, 0, 0, 0><<<gG, TB, 0, stream>>>(hb, w8_h + 6 * HH, w8_l + 6 * HH,
        b_o1, nullptr, nullptr, nullptr, nullptr, 0.f, nullptr, nullptr,
        b1, nullptr, s3, s3 + 128, N);
    mgemm_kernel<128, 1, 0, 0, 0, 0, 0><<<gG, TB, 0, stream>>>(b1, w8_h + 7 * HH, w8_l + 7 * HH,
        b_o2, g_o, bt_o, s3, s3 + 128, invn, nullptr, nullptr,
        out, nullptr, nullptr, nullptr, N);
}

// Round 8
// 917.802 us; speedup vs baseline: 1.0744x; 1.0744x over previous
//
#include <hip/hip_runtime.h>
#include <cstddef>
#include <cstdint>

typedef short short8 __attribute__((ext_vector_type(8)));
typedef unsigned short ushort8v __attribute__((ext_vector_type(8)));
typedef float float16 __attribute__((ext_vector_type(16)));
typedef unsigned short ushort;

namespace {

constexpr int H = 128;

__device__ inline ushort f2bf(float v) {
    unsigned u = __float_as_uint(v);
    unsigned r = u + 0x7fffu + ((u >> 16) & 1u);
    return (ushort)(r >> 16);
}
__device__ inline float bf2f(ushort b) { return __uint_as_float((unsigned)b << 16); }
__device__ inline float blo(unsigned v) { return __uint_as_float(v << 16); }
__device__ inline float bhiF(unsigned v) { return __uint_as_float(v & 0xffff0000u); }

// ---------------- edge-index dtype detection ----------------
__global__ void detect_kernel(const int* __restrict__ ei, int* __restrict__ flag) {
    __shared__ int cnt;
    if (threadIdx.x == 0) cnt = 0;
    __syncthreads();
    int z = 0;
    for (int i = threadIdx.x; i < 2048; i += 256)
        if (ei[2 * i + 1] == 0) z++;
    atomicAdd(&cnt, z);
    __syncthreads();
    if (threadIdx.x == 0) *flag = (cnt > 1024) ? 1 : 0;
}

// ---------------- one-pass: convert + in-degree + CSR fill (ushort, 32+32 spill) ----------------
__global__ void build_kernel(const int* __restrict__ ei, const int* __restrict__ flag,
                             int* __restrict__ degi, int* __restrict__ cnt,
                             ushort* __restrict__ csr, ushort* __restrict__ csr2, int E) {
    int e = blockIdx.x * 256 + threadIdx.x;
    if (e >= E) return;
    int r, c;
    if (*flag) { r = ei[2 * e]; c = ei[2 * (E + e)]; }
    else       { r = ei[e];     c = ei[E + e]; }
    if (r == c) return;
    atomicAdd(&degi[c], 1);
    int slot = atomicAdd(&cnt[r], 1);
    if (slot < 32)      csr [((size_t)r << 5) + slot]      = (ushort)c;
    else if (slot < 64) csr2[((size_t)r << 5) + slot - 32] = (ushort)c;
}

__global__ void dinv_kernel(const int* __restrict__ degi, float* __restrict__ d, int n) {
    int i = blockIdx.x * 256 + threadIdx.x;
    if (i < n) d[i] = rsqrtf(1.0f + (float)degi[i]);
}

// ---------------- panel SpMM: out[r,p] = bf16( dinv[r] * (z[r,p] + sum_nbr z[c,p]) ) ----------------
// z/out PANEL-MAJOR: [panel][node][32 feats] (64 B/node/panel, 3.2 MB/panel -> L2-resident).
// panel = (blockIdx&7)>>1 -> 2 XCDs per panel. One wave per (row,panel); 8 groups x 8 lanes;
// lane loads 8B (4 bf16); each group owns 4 consecutive edges (indices via one 8B csr read);
// deg<=32 fully unrolled with 4 gathers in flight; rare spill loop for deg>32.
__global__ __launch_bounds__(256)
void spmm_kernel(const int* __restrict__ cnt, const ushort* __restrict__ csr,
                 const ushort* __restrict__ csr2, const float* __restrict__ dinv,
                 const ushort* __restrict__ z, ushort* __restrict__ outp, int n) {
    const int s = blockIdx.x & 7;
    const int panel = s >> 1;
    const int wave = threadIdx.x >> 6;
    const int lane = threadIdx.x & 63;
    const int g = lane >> 3, f = lane & 7;
    const int row = (blockIdx.x >> 3) * 8 + (s & 1) * 4 + wave;
    if (row >= n) return;
    const size_t pstr = (size_t)n << 5;          // ushorts per panel
    const ushort* zp = z + panel * pstr;
    ushort* op = outp + panel * pstr;
    int deg = cnt[row]; if (deg > 64) deg = 64;
    const int j0 = g << 2;
    float a0 = 0.f, a1 = 0.f, a2 = 0.f, a3 = 0.f;
    {
        uint2 iv = *(const uint2*)(csr + ((size_t)row << 5) + j0);
        int c[4] = {(int)(iv.x & 0xffff), (int)(iv.x >> 16),
                    (int)(iv.y & 0xffff), (int)(iv.y >> 16)};
        float ss[4];
#pragma unroll
        for (int q = 0; q < 4; ++q) {
            bool in = (j0 + q) < deg;
            c[q] = in ? c[q] : row;
            ss[q] = in ? 1.f : 0.f;
        }
        uint2 v[4];
#pragma unroll
        for (int q = 0; q < 4; ++q)
            v[q] = *(const uint2*)(zp + ((size_t)c[q] << 5) + (f << 2));
#pragma unroll
        for (int q = 0; q < 4; ++q) {
            a0 = fmaf(ss[q], blo(v[q].x), a0);
            a1 = fmaf(ss[q], bhiF(v[q].x), a1);
            a2 = fmaf(ss[q], blo(v[q].y), a2);
            a3 = fmaf(ss[q], bhiF(v[q].y), a3);
        }
    }
    if (deg > 32) {   // rare (P ~ 2e-5): wave-uniform branch
        uint2 iv = *(const uint2*)(csr2 + ((size_t)row << 5) + j0);
        int c[4] = {(int)(iv.x & 0xffff), (int)(iv.x >> 16),
                    (int)(iv.y & 0xffff), (int)(iv.y >> 16)};
        float ss[4];
#pragma unroll
        for (int q = 0; q < 4; ++q) {
            bool in = (32 + j0 + q) < deg;
            c[q] = in ? c[q] : row;
            ss[q] = in ? 1.f : 0.f;
        }
        uint2 v[4];
#pragma unroll
        for (int q = 0; q < 4; ++q)
            v[q] = *(const uint2*)(zp + ((size_t)c[q] << 5) + (f << 2));
#pragma unroll
        for (int q = 0; q < 4; ++q) {
            a0 = fmaf(ss[q], blo(v[q].x), a0);
            a1 = fmaf(ss[q], bhiF(v[q].x), a1);
            a2 = fmaf(ss[q], blo(v[q].y), a2);
            a3 = fmaf(ss[q], bhiF(v[q].y), a3);
        }
    }
#pragma unroll
    for (int dsh = 8; dsh < 64; dsh <<= 1) {
        a0 += __shfl_xor(a0, dsh, 64);
        a1 += __shfl_xor(a1, dsh, 64);
        a2 += __shfl_xor(a2, dsh, 64);
        a3 += __shfl_xor(a3, dsh, 64);
    }
    if (g == 0) {
        uint2 sv = *(const uint2*)(zp + ((size_t)row << 5) + (f << 2));
        float di = dinv[row];
        float r0 = di * (a0 + blo(sv.x));
        float r1 = di * (a1 + bhiF(sv.x));
        float r2 = di * (a2 + blo(sv.y));
        float r3 = di * (a3 + bhiF(sv.y));
        uint2 o;
        o.x = (unsigned)f2bf(r0) | ((unsigned)f2bf(r1) << 16);
        o.y = (unsigned)f2bf(r2) | ((unsigned)f2bf(r3) << 16);
        *(uint2*)(op + ((size_t)row << 5) + (f << 2)) = o;
    }
}

// ---------------- weight prep: split fp32 W[K][128] -> bf16 hi/lo, transposed [n][K] ----------------
__global__ void wprep_in_kernel(const float* __restrict__ W, ushort* __restrict__ hi,
                                ushort* __restrict__ lo) {   // K=64
    int i = blockIdx.x * 256 + threadIdx.x;   // < 64*128
    int k = i >> 7, nn = i & 127;
    float v = W[i];
    ushort h = f2bf(v);
    ushort l = f2bf(v - bf2f(h));
    size_t o = ((size_t)nn << 6) + k;
    hi[o] = h; lo[o] = l;
}

// 8 K=128 matrices: Wf[0..2], Wa[0..2], Wo1, Wo2 -> contiguous [mat][n][K]
__global__ void wprep8_kernel(const float* __restrict__ Wf, const float* __restrict__ Wa,
                              const float* __restrict__ Wo1, const float* __restrict__ Wo2,
                              ushort* __restrict__ hi, ushort* __restrict__ lo) {
    int i = blockIdx.x * 256 + threadIdx.x;   // < 8*16384
    int mat = i >> 14;
    int rem = i & 16383;
    int k = rem >> 7, nn = rem & 127;
    const float* src = (mat < 3) ? Wf + mat * 16384
                     : (mat < 6) ? Wa + (mat - 3) * 16384
                     : (mat == 6) ? Wo1 : Wo2;
    float v = src[rem];
    ushort h = f2bf(v);
    ushort l = f2bf(v - bf2f(h));
    size_t o = ((size_t)mat << 14) + ((size_t)nn << 7) + k;
    hi[o] = h; lo[o] = l;
}

// ---------------- single-barrier MFMA GEMM: (n x K) @ (K x 128) ----------------
// B (hi/lo) staged to LDS ONCE with XOR-swizzled 16B groups. A preloaded to registers.
// ABF=0: A fp32 row-major, split hi/lo (3 MFMAs/frag). ABF=1: A bf16 PANEL-MAJOR 32-wide.
// PRO=1: A' = relu(a*scale+shift), scale/shift finalized in-block from fsum/fsq + g/bt.
// EPI: 0=+bias, 1=sigmoid, 2=*y0^2, 3=*y0. STATS: col sum/sumsq -> ssum/ssq.
// WBF: write ybf = bf16(dinv[r]*v) PANEL-MAJOR 32-wide. NOC: skip fp32 C write.
template <int K, int PRO, int EPI, int STATS, int WBF, int ABF, int NOC>
__global__ __launch_bounds__(256)
void mgemm_kernel(const void* __restrict__ Araw,
                  const ushort* __restrict__ Bhi, const ushort* __restrict__ Blo,
                  const float* __restrict__ bias,
                  const float* __restrict__ g, const float* __restrict__ bt,
                  const float* __restrict__ fsum, const float* __restrict__ fsq, float invn,
                  const float* __restrict__ y0, const float* __restrict__ dinv,
                  float* __restrict__ C, ushort* __restrict__ ybf,
                  float* __restrict__ ssum, float* __restrict__ ssq, int n) {
    constexpr int NG = K / 8;     // 16B groups per B row
    constexpr int GM = NG - 1;    // XOR swizzle mask
    constexpr int NCH = K / 16;   // MFMA K-chunks
    __shared__ __align__(16) ushort lds[2 * 128 * K];   // Bh | Bl (aliased by stats later)
    __shared__ float scs[128], shs[128];
    ushort* Bh = lds;
    ushort* Bl = lds + 128 * K;
    const int tid = threadIdx.x;
    const int lane = tid & 63;
    const int w = tid >> 6;
    const int m = lane & 31;
    const int half = lane >> 5;
    const int rowbase = blockIdx.x * 128;
    const int grow = rowbase + w * 32 + m;
    const bool rok = grow < n;
    const size_t pstr = (size_t)n << 5;   // 32-wide panel stride in ushorts

    if (PRO == 1 && tid < K) {
        float mn = fsum[tid] * invn;
        float var = fmaxf(fsq[tid] * invn - mn * mn, 0.0f);
        float sc = g[tid] * rsqrtf(var + 1e-5f);
        scs[tid] = sc;
        shs[tid] = bt[tid] - mn * sc;
    }

    // --- stage all of B (hi/lo), swizzled ---
    for (int gi = tid; gi < 128 * NG; gi += 256) {
        int nn = gi / NG;
        int gg = gi & GM;
        int dst = nn * K + ((gg ^ (nn & GM)) << 3);
        *(ushort8v*)&Bh[dst] = *(const ushort8v*)(Bhi + (size_t)nn * K + (gg << 3));
        *(ushort8v*)&Bl[dst] = *(const ushort8v*)(Blo + (size_t)nn * K + (gg << 3));
    }

    // --- preload A for the whole K ---
    float4 aR[2 * NCH];
    short8 aB[NCH];
    if (ABF) {
#pragma unroll
        for (int ch = 0; ch < NCH; ++ch) {
            const int k0 = ch * 16 + half * 8;
            const ushort* Ab = (const ushort*)Araw + (size_t)(k0 >> 5) * pstr
                               + ((size_t)grow << 5) + (k0 & 31);
            aB[ch] = rok ? *(const short8*)(Ab) : (short8)(short)0;
        }
    } else {
        const float* A = (const float*)Araw + (size_t)grow * K + half * 8;
#pragma unroll
        for (int ch = 0; ch < NCH; ++ch) {
            aR[2 * ch]     = rok ? *(const float4*)(A + ch * 16)     : make_float4(0.f, 0.f, 0.f, 0.f);
            aR[2 * ch + 1] = rok ? *(const float4*)(A + ch * 16 + 4) : make_float4(0.f, 0.f, 0.f, 0.f);
        }
    }

    __syncthreads();   // the only barrier before the epilogue

    float16 acc[4];
#pragma unroll
    for (int t = 0; t < 4; ++t) acc[t] = (float16)(0.0f);

#pragma unroll
    for (int ch = 0; ch < NCH; ++ch) {
        short8 ah, al;
        if (ABF) {
            ah = aB[ch];
        } else {
            float av[8] = {aR[2 * ch].x,     aR[2 * ch].y,     aR[2 * ch].z,     aR[2 * ch].w,
                           aR[2 * ch + 1].x, aR[2 * ch + 1].y, aR[2 * ch + 1].z, aR[2 * ch + 1].w};
            if (PRO == 1) {
                const int kb = ch * 16 + half * 8;
#pragma unroll
                for (int q = 0; q < 8; ++q)
                    av[q] = fmaxf(fmaf(av[q], scs[kb + q], shs[kb + q]), 0.f);
            }
#pragma unroll
            for (int q = 0; q < 8; ++q) {
                ushort h = f2bf(av[q]);
                ah[q] = (short)h;
                al[q] = (short)f2bf(av[q] - bf2f(h));
            }
        }
        const int gg = 2 * ch + half;
#pragma unroll
        for (int t = 0; t < 4; ++t) {
            const int nn = t * 32 + m;
            const int bo = nn * K + ((gg ^ (nn & GM)) << 3);
            short8 bh = *(const short8*)&Bh[bo];
            short8 bl = *(const short8*)&Bl[bo];
            acc[t] = __builtin_amdgcn_mfma_f32_32x32x16_bf16(ah, bh, acc[t], 0, 0, 0);
            acc[t] = __builtin_amdgcn_mfma_f32_32x32x16_bf16(ah, bl, acc[t], 0, 0, 0);
            if (!ABF)
                acc[t] = __builtin_amdgcn_mfma_f32_32x32x16_bf16(al, bh, acc[t], 0, 0, 0);
        }
    }

    // --- epilogue ---
    float lsum[4], lsq[4];
    if (STATS) {
#pragma unroll
        for (int t = 0; t < 4; ++t) { lsum[t] = 0.f; lsq[t] = 0.f; }
    }
#pragma unroll
    for (int t = 0; t < 4; ++t) {
        const int col = t * 32 + m;
        const float bv = bias ? bias[col] : 0.0f;
        const size_t wboff = WBF ? ((size_t)(col >> 5) * pstr + (col & 31)) : 0;
#pragma unroll
        for (int r = 0; r < 16; ++r) {
            int rowl = w * 32 + (r & 3) + 8 * (r >> 2) + 4 * half;
            int gr = rowbase + rowl;
            if (gr < n) {
                float v = acc[t][r] + bv;
                if (EPI == 1) v = 1.0f / (1.0f + __expf(-v));
                if (EPI == 2 || EPI == 3) {
                    float t0 = y0[(size_t)gr * H + col];
                    v *= (EPI == 2) ? t0 * t0 : t0;
                }
                if (!NOC) C[(size_t)gr * H + col] = v;
                if (WBF) ybf[wboff + ((size_t)gr << 5)] = f2bf(dinv[gr] * v);
                if (STATS) { lsum[t] += v; lsq[t] += v * v; }
            }
        }
    }
    if (STATS) {
        __syncthreads();   // all B-reads done -> safe to alias LDS
        float* csum = (float*)lds;
        float* csq = csum + 128;
        if (tid < 128) { csum[tid] = 0.f; csq[tid] = 0.f; }
        __syncthreads();
#pragma unroll
        for (int t = 0; t < 4; ++t) {
            atomicAdd(&csum[t * 32 + m], lsum[t]);
            atomicAdd(&csq[t * 32 + m], lsq[t]);
        }
        __syncthreads();
        if (tid < 128) {
            atomicAdd(&ssum[tid], csum[tid]);
            atomicAdd(&ssq[tid], csq[tid]);
        }
    }
}

// ---------------- batchnorm apply (in-block finalize) + relu + residual ----------------
__global__ void bn_relu_res_kernel(float* __restrict__ io, const float* __restrict__ res,
                                   const float* __restrict__ fsum, const float* __restrict__ fsq,
                                   const float* __restrict__ g, const float* __restrict__ bt,
                                   float invn, int total4) {
    __shared__ float scs[128], shs[128];
    int tid = threadIdx.x;
    if (tid < 128) {
        float mn = fsum[tid] * invn;
        float var = fmaxf(fsq[tid] * invn - mn * mn, 0.0f);
        float sc = g[tid] * rsqrtf(var + 1e-5f);
        scs[tid] = sc;
        shs[tid] = bt[tid] - mn * sc;
    }
    __syncthreads();
    int i = blockIdx.x * 256 + tid;
    if (i >= total4) return;
    float4 v = ((float4*)io)[i];
    int c = (i << 2) & 127;
    v.x = fmaxf(fmaf(v.x, scs[c],     shs[c]),     0.f);
    v.y = fmaxf(fmaf(v.y, scs[c + 1], shs[c + 1]), 0.f);
    v.z = fmaxf(fmaf(v.z, scs[c + 2], shs[c + 2]), 0.f);
    v.w = fmaxf(fmaf(v.w, scs[c + 3], shs[c + 3]), 0.f);
    if (res) {
        float4 r = ((const float4*)res)[i];
        v.x += r.x; v.y += r.y; v.z += r.z; v.w += r.w;
    }
    ((float4*)io)[i] = v;
}

} // namespace

extern "C" void kernel_launch(void* const* d_in, const int* in_sizes, int n_in,
                              void* d_out, int out_size, void* d_ws, size_t ws_size,
                              hipStream_t stream) {
    const float* x     = (const float*)d_in[0];
    const int*   ei    = (const int*)d_in[1];
    const float* W_in  = (const float*)d_in[2];
    const float* b_in  = (const float*)d_in[3];
    const float* g_in  = (const float*)d_in[4];
    const float* bt_in = (const float*)d_in[5];
    const float* Wf    = (const float*)d_in[6];
    const float* Wa    = (const float*)d_in[7];
    const float* g_nm  = (const float*)d_in[8];
    const float* bt_nm = (const float*)d_in[9];
    const float* W_o1  = (const float*)d_in[10];
    const float* b_o1  = (const float*)d_in[11];
    const float* g_o   = (const float*)d_in[12];
    const float* bt_o  = (const float*)d_in[13];
    const float* W_o2  = (const float*)d_in[14];
    const float* b_o2  = (const float*)d_in[15];
    float* out = (float*)d_out;

    const int N = in_sizes[0] / 64;
    const int E = in_sizes[1] / 2;

    char* wsp = (char*)d_ws;
    size_t off = 0;
    auto alloc = [&](size_t bytes) -> void* {
        void* p = wsp + off;
        off = (off + bytes + 255) & ~(size_t)255;
        return p;
    };
    int*    flag  = (int*)   alloc(4);
    float*  stats = (float*) alloc(4096);                // 4 slices of (ssum128|ssq128)
    ushort* win_h = (ushort*)alloc(64 * H * 2);
    ushort* win_l = (ushort*)alloc(64 * H * 2);
    ushort* w8_h  = (ushort*)alloc(8 * H * H * 2);
    ushort* w8_l  = (ushort*)alloc(8 * H * H * 2);
    int*    cnts  = (int*)   alloc((size_t)2 * N * 4);   // degi | cnt (one memset)
    int*    degi  = cnts;
    int*    cnt   = cnts + N;
    float*  dinv  = (float*) alloc((size_t)N * 4);
    ushort* csr   = (ushort*)alloc((size_t)N * 32 * 2);  // main table (deg<=32)
    ushort* csr2  = (ushort*)alloc((size_t)N * 32 * 2);  // spill (32<deg<=64)
    ushort* zb    = (ushort*)alloc((size_t)N * H * 2);   // panel-major z (dinv-scaled)
    ushort* tz    = (ushort*)alloc((size_t)N * H * 2);   // panel-major spmm output
    float*  b0    = (float*) alloc((size_t)N * H * 4);
    float*  b1    = (float*) alloc((size_t)N * H * 4);
    float*  b3    = (float*) alloc((size_t)N * H * 4);

    float* s0 = stats;
    float* s1 = stats + 256;
    float* s2 = stats + 512;
    float* s3 = stats + 768;

    const int TB = 256;
    const int gE = (E + TB - 1) / TB;
    const int gN = (N + TB - 1) / TB;
    const int gG = (N + 127) / 128;
    const int gS = ((N + 7) / 8) * 8;       // 8 blocks (4 panels x 2 XCD-slots) per 8 rows
    const int gV = (N * H / 4 + TB - 1) / TB;
    const float invn = 1.0f / (float)N;
    const size_t HH = (size_t)H * H;

    // --- graph preprocessing: one pass ---
    detect_kernel<<<1, TB, 0, stream>>>(ei, flag);
    hipMemsetAsync(cnts, 0, (size_t)2 * N * 4, stream);
    hipMemsetAsync(stats, 0, 4096, stream);
    build_kernel<<<gE, TB, 0, stream>>>(ei, flag, degi, cnt, csr, csr2, E);
    dinv_kernel<<<gN, TB, 0, stream>>>(degi, dinv, N);

    // --- weight split prep ---
    wprep_in_kernel<<<(64 * H) / 256, TB, 0, stream>>>(W_in, win_h, win_l);
    wprep8_kernel<<<(8 * H * H) / 256, TB, 0, stream>>>(Wf, Wa, W_o1, W_o2, w8_h, w8_l);

    // --- input encoder: h = relu(BN(x @ W_in + b_in)) -> b0 ---
    mgemm_kernel<64, 0, 0, 1, 0, 0, 0><<<gG, TB, 0, stream>>>(x, win_h, win_l, b_in,
        nullptr, nullptr, nullptr, nullptr, 0.f, nullptr, nullptr,
        b0, nullptr, s0, s0 + 128, N);
    bn_relu_res_kernel<<<gV, TB, 0, stream>>>(b0, nullptr, s0, s0 + 128, g_in, bt_in,
                                              invn, N * H / 4);

    // --- RWKP conv layers ---
    float* hb = b0;
    float* fb = b3;
    float* slayer[2] = {s1, s2};
    for (int l = 0; l < 3; ++l) {
        const ushort* wfh = w8_h + (size_t)l * HH;
        const ushort* wfl = w8_l + (size_t)l * HH;
        const ushort* wah = w8_h + (size_t)(3 + l) * HH;
        const ushort* wal = w8_l + (size_t)(3 + l) * HH;
        // y0 = sigmoid(h @ Wf_l) -> b1 (fp32) + zb (bf16 panel-major, dinv-scaled)
        mgemm_kernel<128, 0, 1, 0, 1, 0, 0><<<gG, TB, 0, stream>>>(hb, wfh, wfl, nullptr,
            nullptr, nullptr, nullptr, nullptr, 0.f, nullptr, dinv,
            b1, zb, nullptr, nullptr, N);
        // t = A*y0 -> tz (bf16 panel-major)
        spmm_kernel<<<gS, TB, 0, stream>>>(cnt, csr, csr2, dinv, zb, tz, N);
        // y1 = y0^2 * (t @ Wa_l) -> zb only (bf16 panel-major, dinv-scaled)
        mgemm_kernel<128, 0, 2, 0, 1, 1, 1><<<gG, TB, 0, stream>>>(tz, wah, wal, nullptr,
            nullptr, nullptr, nullptr, nullptr, 0.f, b1, dinv,
            nullptr, zb, nullptr, nullptr, N);
        // t = A*y1 -> tz (bf16 panel-major)
        spmm_kernel<<<gS, TB, 0, stream>>>(cnt, csr, csr2, dinv, zb, tz, N);
        // hc = y0 * (t @ Wa_l) -> fb (fp32)
        if (l < 2) {
            float* sl = slayer[l];
            mgemm_kernel<128, 0, 3, 1, 0, 1, 0><<<gG, TB, 0, stream>>>(tz, wah, wal, nullptr,
                nullptr, nullptr, nullptr, nullptr, 0.f, b1, nullptr,
                fb, nullptr, sl, sl + 128, N);
            bn_relu_res_kernel<<<gV, TB, 0, stream>>>(fb, hb, sl, sl + 128,
                g_nm + l * H, bt_nm + l * H, invn, N * H / 4);
            float* t = hb; hb = fb; fb = t;
        } else {
            mgemm_kernel<128, 0, 3, 0, 0, 1, 0><<<gG, TB, 0, stream>>>(tz, wah, wal, nullptr,
                nullptr, nullptr, nullptr, nullptr, 0.f, b1, nullptr,
                fb, nullptr, nullptr, nullptr, N);
            hb = fb;
        }
    }

    // --- output encoder ---
    mgemm_kernel<128, 0, 0, 1, 0, 0, 0><<<gG, TB, 0, stream>>>(hb, w8_h + 6 * HH, w8_l + 6 * HH,
        b_o1, nullptr, nullptr, nullptr, nullptr, 0.f, nullptr, nullptr,
        b1, nullptr, s3, s3 + 128, N);
    mgemm_kernel<128, 1, 0, 0, 0, 0, 0><<<gG, TB, 0, stream>>>(b1, w8_h + 7 * HH, w8_l + 7 * HH,
        b_o2, g_o, bt_o, s3, s3 + 128, invn, nullptr, nullptr,
        out, nullptr, nullptr, nullptr, N);
}

// Round 9
// 793.939 us; speedup vs baseline: 1.2420x; 1.1560x over previous
//
#include <hip/hip_runtime.h>
#include <cstddef>
#include <cstdint>

typedef short short8 __attribute__((ext_vector_type(8)));
typedef unsigned short ushort8v __attribute__((ext_vector_type(8)));
typedef float float16 __attribute__((ext_vector_type(16)));
typedef unsigned short ushort;

namespace {

constexpr int H = 128;

__device__ inline ushort f2bf(float v) {
    unsigned u = __float_as_uint(v);
    unsigned r = u + 0x7fffu + ((u >> 16) & 1u);
    return (ushort)(r >> 16);
}
__device__ inline float bf2f(ushort b) { return __uint_as_float((unsigned)b << 16); }
__device__ inline float blo(unsigned v) { return __uint_as_float(v << 16); }
__device__ inline float bhiF(unsigned v) { return __uint_as_float(v & 0xffff0000u); }

// ---------------- edge-index dtype detection ----------------
__global__ void detect_kernel(const int* __restrict__ ei, int* __restrict__ flag) {
    __shared__ int cnt;
    if (threadIdx.x == 0) cnt = 0;
    __syncthreads();
    int z = 0;
    for (int i = threadIdx.x; i < 2048; i += 256)
        if (ei[2 * i + 1] == 0) z++;
    atomicAdd(&cnt, z);
    __syncthreads();
    if (threadIdx.x == 0) *flag = (cnt > 1024) ? 1 : 0;
}

// ---------------- one-pass: convert + in-degree + CSR fill (ushort, 32+32 spill) ----------------
__global__ void build_kernel(const int* __restrict__ ei, const int* __restrict__ flag,
                             int* __restrict__ degi, int* __restrict__ cnt,
                             ushort* __restrict__ csr, ushort* __restrict__ csr2, int E) {
    int e = blockIdx.x * 256 + threadIdx.x;
    if (e >= E) return;
    int r, c;
    if (*flag) { r = ei[2 * e]; c = ei[2 * (E + e)]; }
    else       { r = ei[e];     c = ei[E + e]; }
    if (r == c) return;
    atomicAdd(&degi[c], 1);
    int slot = atomicAdd(&cnt[r], 1);
    if (slot < 32)      csr [((size_t)r << 5) + slot]      = (ushort)c;
    else if (slot < 64) csr2[((size_t)r << 5) + slot - 32] = (ushort)c;
}

__global__ void dinv_kernel(const int* __restrict__ degi, float* __restrict__ d, int n) {
    int i = blockIdx.x * 256 + threadIdx.x;
    if (i < n) d[i] = rsqrtf(1.0f + (float)degi[i]);
}

// ---------------- quartet panel SpMM ----------------
// z/out PANEL-MAJOR: [panel][node][32 feats] (64 B/node/panel, 3.2 MB/panel -> L2-resident;
// panel = (blockIdx&7)>>1 -> 2 XCDs per panel). Wave = 4 consecutive rows x 1 panel;
// 16 lanes per row (16 x 4B = the 64B panel row). Per-quarter DIVERGENT loop to own degree:
// no clamping, no wasted gathers, no butterfly, all lanes write. 4-edge chunks (one uint2
// broadcast index load, 4 gathers in flight), 1-edge remainder, rare spill (deg>32).
__global__ __launch_bounds__(256)
void spmm_kernel(const int* __restrict__ cnt, const ushort* __restrict__ csr,
                 const ushort* __restrict__ csr2, const float* __restrict__ dinv,
                 const ushort* __restrict__ z, ushort* __restrict__ outp, int n) {
    const int s = blockIdx.x & 7;
    const int panel = s >> 1;
    const int wave = threadIdx.x >> 6;
    const int lane = threadIdx.x & 63;
    const int q = lane >> 4;        // quarter -> row within quartet
    const int f = lane & 15;        // feature-pair (4B) within panel
    const int row = (blockIdx.x >> 3) * 32 + (s & 1) * 16 + wave * 4 + q;
    if (row >= n) return;
    const size_t pstr = (size_t)n << 5;          // ushorts per panel
    const ushort* zp = z + panel * pstr;
    const unsigned foff = (unsigned)(f << 1);
    int deg = cnt[row];
    int degm = deg > 32 ? 32 : deg;
    const ushort* ci = csr + ((size_t)row << 5);
    unsigned sv = *(const unsigned*)(zp + ((size_t)row << 5) + foff);
    float ax = blo(sv), ay = bhiF(sv);
    int j = 0;
    for (; j + 4 <= degm; j += 4) {
        uint2 iv = *(const uint2*)(ci + j);      // 4 edge ids, broadcast within quarter
        int c0 = (int)(iv.x & 0xffff), c1 = (int)(iv.x >> 16);
        int c2 = (int)(iv.y & 0xffff), c3 = (int)(iv.y >> 16);
        unsigned v0 = *(const unsigned*)(zp + ((size_t)c0 << 5) + foff);
        unsigned v1 = *(const unsigned*)(zp + ((size_t)c1 << 5) + foff);
        unsigned v2 = *(const unsigned*)(zp + ((size_t)c2 << 5) + foff);
        unsigned v3 = *(const unsigned*)(zp + ((size_t)c3 << 5) + foff);
        ax += blo(v0); ay += bhiF(v0);
        ax += blo(v1); ay += bhiF(v1);
        ax += blo(v2); ay += bhiF(v2);
        ax += blo(v3); ay += bhiF(v3);
    }
    for (; j < degm; ++j) {
        int c = (int)ci[j];
        unsigned v = *(const unsigned*)(zp + ((size_t)c << 5) + foff);
        ax += blo(v); ay += bhiF(v);
    }
    if (deg > 32) {   // rare (P ~ 2e-5)
        int dm = deg > 64 ? 64 : deg;
        const ushort* c2p = csr2 + ((size_t)row << 5);
        for (int k = 32; k < dm; ++k) {
            int c = (int)c2p[k - 32];
            unsigned v = *(const unsigned*)(zp + ((size_t)c << 5) + foff);
            ax += blo(v); ay += bhiF(v);
        }
    }
    float di = dinv[row];
    unsigned o = (unsigned)f2bf(di * ax) | ((unsigned)f2bf(di * ay) << 16);
    *(unsigned*)(outp + panel * pstr + ((size_t)row << 5) + foff) = o;
}

// ---------------- weight prep: split fp32 W[K][128] -> bf16 hi/lo, transposed [n][K] ----------------
__global__ void wprep_in_kernel(const float* __restrict__ W, ushort* __restrict__ hi,
                                ushort* __restrict__ lo) {   // K=64
    int i = blockIdx.x * 256 + threadIdx.x;   // < 64*128
    int k = i >> 7, nn = i & 127;
    float v = W[i];
    ushort h = f2bf(v);
    ushort l = f2bf(v - bf2f(h));
    size_t o = ((size_t)nn << 6) + k;
    hi[o] = h; lo[o] = l;
}

// 8 K=128 matrices: Wf[0..2], Wa[0..2], Wo1, Wo2 -> contiguous [mat][n][K]
__global__ void wprep8_kernel(const float* __restrict__ Wf, const float* __restrict__ Wa,
                              const float* __restrict__ Wo1, const float* __restrict__ Wo2,
                              ushort* __restrict__ hi, ushort* __restrict__ lo) {
    int i = blockIdx.x * 256 + threadIdx.x;   // < 8*16384
    int mat = i >> 14;
    int rem = i & 16383;
    int k = rem >> 7, nn = rem & 127;
    const float* src = (mat < 3) ? Wf + mat * 16384
                     : (mat < 6) ? Wa + (mat - 3) * 16384
                     : (mat == 6) ? Wo1 : Wo2;
    float v = src[rem];
    ushort h = f2bf(v);
    ushort l = f2bf(v - bf2f(h));
    size_t o = ((size_t)mat << 14) + ((size_t)nn << 7) + k;
    hi[o] = h; lo[o] = l;
}

// ---------------- single-barrier MFMA GEMM: (n x K) @ (K x 128) ----------------
// B (hi/lo) staged to LDS ONCE with XOR-swizzled 16B groups. A preloaded to registers.
// ABF=0: A fp32 row-major, split hi/lo (3 MFMAs/frag). ABF=1: A bf16 PANEL-MAJOR 32-wide.
// PRO=1: A' = relu(a*scale+shift), scale/shift finalized in-block from fsum/fsq + g/bt.
// EPI: 0=+bias, 1=sigmoid, 2=*y0^2, 3=*y0. STATS: col sum/sumsq -> ssum/ssq.
// WBF: write ybf = bf16(dinv[r]*v) PANEL-MAJOR 32-wide. NOC: skip fp32 C write.
template <int K, int PRO, int EPI, int STATS, int WBF, int ABF, int NOC>
__global__ __launch_bounds__(256)
void mgemm_kernel(const void* __restrict__ Araw,
                  const ushort* __restrict__ Bhi, const ushort* __restrict__ Blo,
                  const float* __restrict__ bias,
                  const float* __restrict__ g, const float* __restrict__ bt,
                  const float* __restrict__ fsum, const float* __restrict__ fsq, float invn,
                  const float* __restrict__ y0, const float* __restrict__ dinv,
                  float* __restrict__ C, ushort* __restrict__ ybf,
                  float* __restrict__ ssum, float* __restrict__ ssq, int n) {
    constexpr int NG = K / 8;     // 16B groups per B row
    constexpr int GM = NG - 1;    // XOR swizzle mask
    constexpr int NCH = K / 16;   // MFMA K-chunks
    __shared__ __align__(16) ushort lds[2 * 128 * K];   // Bh | Bl (aliased by stats later)
    __shared__ float scs[128], shs[128];
    ushort* Bh = lds;
    ushort* Bl = lds + 128 * K;
    const int tid = threadIdx.x;
    const int lane = tid & 63;
    const int w = tid >> 6;
    const int m = lane & 31;
    const int half = lane >> 5;
    const int rowbase = blockIdx.x * 128;
    const int grow = rowbase + w * 32 + m;
    const bool rok = grow < n;
    const size_t pstr = (size_t)n << 5;   // 32-wide panel stride in ushorts

    if (PRO == 1 && tid < K) {
        float mn = fsum[tid] * invn;
        float var = fmaxf(fsq[tid] * invn - mn * mn, 0.0f);
        float sc = g[tid] * rsqrtf(var + 1e-5f);
        scs[tid] = sc;
        shs[tid] = bt[tid] - mn * sc;
    }

    // --- stage all of B (hi/lo), swizzled ---
    for (int gi = tid; gi < 128 * NG; gi += 256) {
        int nn = gi / NG;
        int gg = gi & GM;
        int dst = nn * K + ((gg ^ (nn & GM)) << 3);
        *(ushort8v*)&Bh[dst] = *(const ushort8v*)(Bhi + (size_t)nn * K + (gg << 3));
        *(ushort8v*)&Bl[dst] = *(const ushort8v*)(Blo + (size_t)nn * K + (gg << 3));
    }

    // --- preload A for the whole K ---
    float4 aR[2 * NCH];
    short8 aB[NCH];
    if (ABF) {
#pragma unroll
        for (int ch = 0; ch < NCH; ++ch) {
            const int k0 = ch * 16 + half * 8;
            const ushort* Ab = (const ushort*)Araw + (size_t)(k0 >> 5) * pstr
                               + ((size_t)grow << 5) + (k0 & 31);
            aB[ch] = rok ? *(const short8*)(Ab) : (short8)(short)0;
        }
    } else {
        const float* A = (const float*)Araw + (size_t)grow * K + half * 8;
#pragma unroll
        for (int ch = 0; ch < NCH; ++ch) {
            aR[2 * ch]     = rok ? *(const float4*)(A + ch * 16)     : make_float4(0.f, 0.f, 0.f, 0.f);
            aR[2 * ch + 1] = rok ? *(const float4*)(A + ch * 16 + 4) : make_float4(0.f, 0.f, 0.f, 0.f);
        }
    }

    __syncthreads();   // the only barrier before the epilogue

    float16 acc[4];
#pragma unroll
    for (int t = 0; t < 4; ++t) acc[t] = (float16)(0.0f);

#pragma unroll
    for (int ch = 0; ch < NCH; ++ch) {
        short8 ah, al;
        if (ABF) {
            ah = aB[ch];
        } else {
            float av[8] = {aR[2 * ch].x,     aR[2 * ch].y,     aR[2 * ch].z,     aR[2 * ch].w,
                           aR[2 * ch + 1].x, aR[2 * ch + 1].y, aR[2 * ch + 1].z, aR[2 * ch + 1].w};
            if (PRO == 1) {
                const int kb = ch * 16 + half * 8;
#pragma unroll
                for (int q = 0; q < 8; ++q)
                    av[q] = fmaxf(fmaf(av[q], scs[kb + q], shs[kb + q]), 0.f);
            }
#pragma unroll
            for (int q = 0; q < 8; ++q) {
                ushort h = f2bf(av[q]);
                ah[q] = (short)h;
                al[q] = (short)f2bf(av[q] - bf2f(h));
            }
        }
        const int gg = 2 * ch + half;
#pragma unroll
        for (int t = 0; t < 4; ++t) {
            const int nn = t * 32 + m;
            const int bo = nn * K + ((gg ^ (nn & GM)) << 3);
            short8 bh = *(const short8*)&Bh[bo];
            short8 bl = *(const short8*)&Bl[bo];
            acc[t] = __builtin_amdgcn_mfma_f32_32x32x16_bf16(ah, bh, acc[t], 0, 0, 0);
            acc[t] = __builtin_amdgcn_mfma_f32_32x32x16_bf16(ah, bl, acc[t], 0, 0, 0);
            if (!ABF)
                acc[t] = __builtin_amdgcn_mfma_f32_32x32x16_bf16(al, bh, acc[t], 0, 0, 0);
        }
    }

    // --- epilogue ---
    float lsum[4], lsq[4];
    if (STATS) {
#pragma unroll
        for (int t = 0; t < 4; ++t) { lsum[t] = 0.f; lsq[t] = 0.f; }
    }
#pragma unroll
    for (int t = 0; t < 4; ++t) {
        const int col = t * 32 + m;
        const float bv = bias ? bias[col] : 0.0f;
        const size_t wboff = WBF ? ((size_t)(col >> 5) * pstr + (col & 31)) : 0;
#pragma unroll
        for (int r = 0; r < 16; ++r) {
            int rowl = w * 32 + (r & 3) + 8 * (r >> 2) + 4 * half;
            int gr = rowbase + rowl;
            if (gr < n) {
                float v = acc[t][r] + bv;
                if (EPI == 1) v = 1.0f / (1.0f + __expf(-v));
                if (EPI == 2 || EPI == 3) {
                    float t0 = y0[(size_t)gr * H + col];
                    v *= (EPI == 2) ? t0 * t0 : t0;
                }
                if (!NOC) C[(size_t)gr * H + col] = v;
                if (WBF) ybf[wboff + ((size_t)gr << 5)] = f2bf(dinv[gr] * v);
                if (STATS) { lsum[t] += v; lsq[t] += v * v; }
            }
        }
    }
    if (STATS) {
        __syncthreads();   // all B-reads done -> safe to alias LDS
        float* csum = (float*)lds;
        float* csq = csum + 128;
        if (tid < 128) { csum[tid] = 0.f; csq[tid] = 0.f; }
        __syncthreads();
#pragma unroll
        for (int t = 0; t < 4; ++t) {
            atomicAdd(&csum[t * 32 + m], lsum[t]);
            atomicAdd(&csq[t * 32 + m], lsq[t]);
        }
        __syncthreads();
        if (tid < 128) {
            atomicAdd(&ssum[tid], csum[tid]);
            atomicAdd(&ssq[tid], csq[tid]);
        }
    }
}

// ---------------- batchnorm apply (in-block finalize) + relu + residual ----------------
__global__ void bn_relu_res_kernel(float* __restrict__ io, const float* __restrict__ res,
                                   const float* __restrict__ fsum, const float* __restrict__ fsq,
                                   const float* __restrict__ g, const float* __restrict__ bt,
                                   float invn, int total4) {
    __shared__ float scs[128], shs[128];
    int tid = threadIdx.x;
    if (tid < 128) {
        float mn = fsum[tid] * invn;
        float var = fmaxf(fsq[tid] * invn - mn * mn, 0.0f);
        float sc = g[tid] * rsqrtf(var + 1e-5f);
        scs[tid] = sc;
        shs[tid] = bt[tid] - mn * sc;
    }
    __syncthreads();
    int i = blockIdx.x * 256 + tid;
    if (i >= total4) return;
    float4 v = ((float4*)io)[i];
    int c = (i << 2) & 127;
    v.x = fmaxf(fmaf(v.x, scs[c],     shs[c]),     0.f);
    v.y = fmaxf(fmaf(v.y, scs[c + 1], shs[c + 1]), 0.f);
    v.z = fmaxf(fmaf(v.z, scs[c + 2], shs[c + 2]), 0.f);
    v.w = fmaxf(fmaf(v.w, scs[c + 3], shs[c + 3]), 0.f);
    if (res) {
        float4 r = ((const float4*)res)[i];
        v.x += r.x; v.y += r.y; v.z += r.z; v.w += r.w;
    }
    ((float4*)io)[i] = v;
}

} // namespace

extern "C" void kernel_launch(void* const* d_in, const int* in_sizes, int n_in,
                              void* d_out, int out_size, void* d_ws, size_t ws_size,
                              hipStream_t stream) {
    const float* x     = (const float*)d_in[0];
    const int*   ei    = (const int*)d_in[1];
    const float* W_in  = (const float*)d_in[2];
    const float* b_in  = (const float*)d_in[3];
    const float* g_in  = (const float*)d_in[4];
    const float* bt_in = (const float*)d_in[5];
    const float* Wf    = (const float*)d_in[6];
    const float* Wa    = (const float*)d_in[7];
    const float* g_nm  = (const float*)d_in[8];
    const float* bt_nm = (const float*)d_in[9];
    const float* W_o1  = (const float*)d_in[10];
    const float* b_o1  = (const float*)d_in[11];
    const float* g_o   = (const float*)d_in[12];
    const float* bt_o  = (const float*)d_in[13];
    const float* W_o2  = (const float*)d_in[14];
    const float* b_o2  = (const float*)d_in[15];
    float* out = (float*)d_out;

    const int N = in_sizes[0] / 64;
    const int E = in_sizes[1] / 2;

    char* wsp = (char*)d_ws;
    size_t off = 0;
    auto alloc = [&](size_t bytes) -> void* {
        void* p = wsp + off;
        off = (off + bytes + 255) & ~(size_t)255;
        return p;
    };
    int*    flag  = (int*)   alloc(4);
    float*  stats = (float*) alloc(4096);                // 4 slices of (ssum128|ssq128)
    ushort* win_h = (ushort*)alloc(64 * H * 2);
    ushort* win_l = (ushort*)alloc(64 * H * 2);
    ushort* w8_h  = (ushort*)alloc(8 * H * H * 2);
    ushort* w8_l  = (ushort*)alloc(8 * H * H * 2);
    int*    cnts  = (int*)   alloc((size_t)2 * N * 4);   // degi | cnt (one memset)
    int*    degi  = cnts;
    int*    cnt   = cnts + N;
    float*  dinv  = (float*) alloc((size_t)N * 4);
    ushort* csr   = (ushort*)alloc((size_t)N * 32 * 2);  // main table (deg<=32)
    ushort* csr2  = (ushort*)alloc((size_t)N * 32 * 2);  // spill (32<deg<=64)
    ushort* zb    = (ushort*)alloc((size_t)N * H * 2);   // panel-major z (dinv-scaled)
    ushort* tz    = (ushort*)alloc((size_t)N * H * 2);   // panel-major spmm output
    float*  b0    = (float*) alloc((size_t)N * H * 4);
    float*  b1    = (float*) alloc((size_t)N * H * 4);
    float*  b3    = (float*) alloc((size_t)N * H * 4);

    float* s0 = stats;
    float* s1 = stats + 256;
    float* s2 = stats + 512;
    float* s3 = stats + 768;

    const int TB = 256;
    const int gE = (E + TB - 1) / TB;
    const int gN = (N + TB - 1) / TB;
    const int gG = (N + 127) / 128;
    const int gS = ((N + 31) / 32) * 8;     // 8 blocks (4 panels x 2 row-halves) per 32 rows
    const int gV = (N * H / 4 + TB - 1) / TB;
    const float invn = 1.0f / (float)N;
    const size_t HH = (size_t)H * H;

    // --- graph preprocessing: one pass ---
    detect_kernel<<<1, TB, 0, stream>>>(ei, flag);
    hipMemsetAsync(cnts, 0, (size_t)2 * N * 4, stream);
    hipMemsetAsync(stats, 0, 4096, stream);
    build_kernel<<<gE, TB, 0, stream>>>(ei, flag, degi, cnt, csr, csr2, E);
    dinv_kernel<<<gN, TB, 0, stream>>>(degi, dinv, N);

    // --- weight split prep ---
    wprep_in_kernel<<<(64 * H) / 256, TB, 0, stream>>>(W_in, win_h, win_l);
    wprep8_kernel<<<(8 * H * H) / 256, TB, 0, stream>>>(Wf, Wa, W_o1, W_o2, w8_h, w8_l);

    // --- input encoder: h = relu(BN(x @ W_in + b_in)) -> b0 ---
    mgemm_kernel<64, 0, 0, 1, 0, 0, 0><<<gG, TB, 0, stream>>>(x, win_h, win_l, b_in,
        nullptr, nullptr, nullptr, nullptr, 0.f, nullptr, nullptr,
        b0, nullptr, s0, s0 + 128, N);
    bn_relu_res_kernel<<<gV, TB, 0, stream>>>(b0, nullptr, s0, s0 + 128, g_in, bt_in,
                                              invn, N * H / 4);

    // --- RWKP conv layers ---
    float* hb = b0;
    float* fb = b3;
    float* slayer[2] = {s1, s2};
    for (int l = 0; l < 3; ++l) {
        const ushort* wfh = w8_h + (size_t)l * HH;
        const ushort* wfl = w8_l + (size_t)l * HH;
        const ushort* wah = w8_h + (size_t)(3 + l) * HH;
        const ushort* wal = w8_l + (size_t)(3 + l) * HH;
        // y0 = sigmoid(h @ Wf_l) -> b1 (fp32) + zb (bf16 panel-major, dinv-scaled)
        mgemm_kernel<128, 0, 1, 0, 1, 0, 0><<<gG, TB, 0, stream>>>(hb, wfh, wfl, nullptr,
            nullptr, nullptr, nullptr, nullptr, 0.f, nullptr, dinv,
            b1, zb, nullptr, nullptr, N);
        // t = A*y0 -> tz (bf16 panel-major)
        spmm_kernel<<<gS, TB, 0, stream>>>(cnt, csr, csr2, dinv, zb, tz, N);
        // y1 = y0^2 * (t @ Wa_l) -> zb only (bf16 panel-major, dinv-scaled)
        mgemm_kernel<128, 0, 2, 0, 1, 1, 1><<<gG, TB, 0, stream>>>(tz, wah, wal, nullptr,
            nullptr, nullptr, nullptr, nullptr, 0.f, b1, dinv,
            nullptr, zb, nullptr, nullptr, N);
        // t = A*y1 -> tz (bf16 panel-major)
        spmm_kernel<<<gS, TB, 0, stream>>>(cnt, csr, csr2, dinv, zb, tz, N);
        // hc = y0 * (t @ Wa_l) -> fb (fp32)
        if (l < 2) {
            float* sl = slayer[l];
            mgemm_kernel<128, 0, 3, 1, 0, 1, 0><<<gG, TB, 0, stream>>>(tz, wah, wal, nullptr,
                nullptr, nullptr, nullptr, nullptr, 0.f, b1, nullptr,
                fb, nullptr, sl, sl + 128, N);
            bn_relu_res_kernel<<<gV, TB, 0, stream>>>(fb, hb, sl, sl + 128,
                g_nm + l * H, bt_nm + l * H, invn, N * H / 4);
            float* t = hb; hb = fb; fb = t;
        } else {
            mgemm_kernel<128, 0, 3, 0, 0, 1, 0><<<gG, TB, 0, stream>>>(tz, wah, wal, nullptr,
                nullptr, nullptr, nullptr, nullptr, 0.f, b1, nullptr,
                fb, nullptr, nullptr, nullptr, N);
            hb = fb;
        }
    }

    // --- output encoder ---
    mgemm_kernel<128, 0, 0, 1, 0, 0, 0><<<gG, TB, 0, stream>>>(hb, w8_h + 6 * HH, w8_l + 6 * HH,
        b_o1, nullptr, nullptr, nullptr, nullptr, 0.f, nullptr, nullptr,
        b1, nullptr, s3, s3 + 128, N);
    mgemm_kernel<128, 1, 0, 0, 0, 0, 0><<<gG, TB, 0, stream>>>(b1, w8_h + 7 * HH, w8_l + 7 * HH,
        b_o2, g_o, bt_o, s3, s3 + 128, invn, nullptr, nullptr,
        out, nullptr, nullptr, nullptr, N);
}

// Round 10
// 790.642 us; speedup vs baseline: 1.2472x; 1.0042x over previous
//
#include <hip/hip_runtime.h>
#include <cstddef>
#include <cstdint>

typedef short short8 __attribute__((ext_vector_type(8)));
typedef unsigned short ushort8v __attribute__((ext_vector_type(8)));
typedef float float16 __attribute__((ext_vector_type(16)));
typedef unsigned short ushort;

namespace {

constexpr int H = 128;

__device__ inline ushort f2bf(float v) {
    unsigned u = __float_as_uint(v);
    unsigned r = u + 0x7fffu + ((u >> 16) & 1u);
    return (ushort)(r >> 16);
}
__device__ inline float bf2f(ushort b) { return __uint_as_float((unsigned)b << 16); }
__device__ inline float blo(unsigned v) { return __uint_as_float(v << 16); }
__device__ inline float bhiF(unsigned v) { return __uint_as_float(v & 0xffff0000u); }

// ---------------- edge-index dtype detection ----------------
__global__ void detect_kernel(const int* __restrict__ ei, int* __restrict__ flag) {
    __shared__ int cnt;
    if (threadIdx.x == 0) cnt = 0;
    __syncthreads();
    int z = 0;
    for (int i = threadIdx.x; i < 2048; i += 256)
        if (ei[2 * i + 1] == 0) z++;
    atomicAdd(&cnt, z);
    __syncthreads();
    if (threadIdx.x == 0) *flag = (cnt > 1024) ? 1 : 0;
}

// ---------------- one-pass: convert + in-degree + CSR fill (ushort, 32+32 spill) ----------------
__global__ void build_kernel(const int* __restrict__ ei, const int* __restrict__ flag,
                             int* __restrict__ degi, int* __restrict__ cnt,
                             ushort* __restrict__ csr, ushort* __restrict__ csr2, int E) {
    int e = blockIdx.x * 256 + threadIdx.x;
    if (e >= E) return;
    int r, c;
    if (*flag) { r = ei[2 * e]; c = ei[2 * (E + e)]; }
    else       { r = ei[e];     c = ei[E + e]; }
    if (r == c) return;
    atomicAdd(&degi[c], 1);
    int slot = atomicAdd(&cnt[r], 1);
    if (slot < 32)      csr [((size_t)r << 5) + slot]      = (ushort)c;
    else if (slot < 64) csr2[((size_t)r << 5) + slot - 32] = (ushort)c;
}

__global__ void dinv_kernel(const int* __restrict__ degi, float* __restrict__ d, int n) {
    int i = blockIdx.x * 256 + threadIdx.x;
    if (i < n) d[i] = rsqrtf(1.0f + (float)degi[i]);
}

// ---------------- quartet panel SpMM ----------------
// z/out PANEL-MAJOR: [panel][node][32 feats] (64 B/node/panel, 3.2 MB/panel -> L2-resident;
// panel = (blockIdx&7)>>1 -> 2 XCDs per panel). Wave = 4 consecutive rows x 1 panel;
// 16 lanes per row. Per-quarter divergent loop to own degree; 4-edge chunks.
__global__ __launch_bounds__(256)
void spmm_kernel(const int* __restrict__ cnt, const ushort* __restrict__ csr,
                 const ushort* __restrict__ csr2, const float* __restrict__ dinv,
                 const ushort* __restrict__ z, ushort* __restrict__ outp, int n) {
    const int s = blockIdx.x & 7;
    const int panel = s >> 1;
    const int wave = threadIdx.x >> 6;
    const int lane = threadIdx.x & 63;
    const int q = lane >> 4;        // quarter -> row within quartet
    const int f = lane & 15;        // feature-pair (4B) within panel
    const int row = (blockIdx.x >> 3) * 32 + (s & 1) * 16 + wave * 4 + q;
    if (row >= n) return;
    const size_t pstr = (size_t)n << 5;          // ushorts per panel
    const ushort* zp = z + panel * pstr;
    const unsigned foff = (unsigned)(f << 1);
    int deg = cnt[row];
    int degm = deg > 32 ? 32 : deg;
    const ushort* ci = csr + ((size_t)row << 5);
    unsigned sv = *(const unsigned*)(zp + ((size_t)row << 5) + foff);
    float ax = blo(sv), ay = bhiF(sv);
    int j = 0;
    for (; j + 4 <= degm; j += 4) {
        uint2 iv = *(const uint2*)(ci + j);      // 4 edge ids, broadcast within quarter
        int c0 = (int)(iv.x & 0xffff), c1 = (int)(iv.x >> 16);
        int c2 = (int)(iv.y & 0xffff), c3 = (int)(iv.y >> 16);
        unsigned v0 = *(const unsigned*)(zp + ((size_t)c0 << 5) + foff);
        unsigned v1 = *(const unsigned*)(zp + ((size_t)c1 << 5) + foff);
        unsigned v2 = *(const unsigned*)(zp + ((size_t)c2 << 5) + foff);
        unsigned v3 = *(const unsigned*)(zp + ((size_t)c3 << 5) + foff);
        ax += blo(v0); ay += bhiF(v0);
        ax += blo(v1); ay += bhiF(v1);
        ax += blo(v2); ay += bhiF(v2);
        ax += blo(v3); ay += bhiF(v3);
    }
    for (; j < degm; ++j) {
        int c = (int)ci[j];
        unsigned v = *(const unsigned*)(zp + ((size_t)c << 5) + foff);
        ax += blo(v); ay += bhiF(v);
    }
    if (deg > 32) {   // rare (P ~ 2e-5)
        int dm = deg > 64 ? 64 : deg;
        const ushort* c2p = csr2 + ((size_t)row << 5);
        for (int k = 32; k < dm; ++k) {
            int c = (int)c2p[k - 32];
            unsigned v = *(const unsigned*)(zp + ((size_t)c << 5) + foff);
            ax += blo(v); ay += bhiF(v);
        }
    }
    float di = dinv[row];
    unsigned o = (unsigned)f2bf(di * ax) | ((unsigned)f2bf(di * ay) << 16);
    *(unsigned*)(outp + panel * pstr + ((size_t)row << 5) + foff) = o;
}

// ---------------- weight prep: split fp32 W[K][128] -> bf16 hi/lo, transposed [n][K] ----------------
__global__ void wprep_in_kernel(const float* __restrict__ W, ushort* __restrict__ hi,
                                ushort* __restrict__ lo) {   // K=64
    int i = blockIdx.x * 256 + threadIdx.x;   // < 64*128
    int k = i >> 7, nn = i & 127;
    float v = W[i];
    ushort h = f2bf(v);
    ushort l = f2bf(v - bf2f(h));
    size_t o = ((size_t)nn << 6) + k;
    hi[o] = h; lo[o] = l;
}

// 8 K=128 matrices: Wf[0..2], Wa[0..2], Wo1, Wo2 -> contiguous [mat][n][K]
__global__ void wprep8_kernel(const float* __restrict__ Wf, const float* __restrict__ Wa,
                              const float* __restrict__ Wo1, const float* __restrict__ Wo2,
                              ushort* __restrict__ hi, ushort* __restrict__ lo) {
    int i = blockIdx.x * 256 + threadIdx.x;   // < 8*16384
    int mat = i >> 14;
    int rem = i & 16383;
    int k = rem >> 7, nn = rem & 127;
    const float* src = (mat < 3) ? Wf + mat * 16384
                     : (mat < 6) ? Wa + (mat - 3) * 16384
                     : (mat == 6) ? Wo1 : Wo2;
    float v = src[rem];
    ushort h = f2bf(v);
    ushort l = f2bf(v - bf2f(h));
    size_t o = ((size_t)mat << 14) + ((size_t)nn << 7) + k;
    hi[o] = h; lo[o] = l;
}

// ---------------- K-chunked MFMA GEMM: (n x K) @ (K x 128) ----------------
// B (hi/lo) staged to LDS in 64-K chunks (32 KB -> 4 blocks/CU), XOR-swizzled 16B groups.
// A preloaded to registers per chunk. 1 barrier for K=64, 3 for K=128.
// ABF=0: A fp32 row-major, split hi/lo (3 MFMAs/frag). ABF=1: A bf16 PANEL-MAJOR 32-wide.
// PRO=1: A' = relu(a*scale+shift), scale/shift finalized in-block from fsum/fsq + g/bt.
// EPI: 0=+bias, 1=sigmoid, 2=*y0^2, 3=*y0. STATS: col sum/sumsq -> ssum/ssq.
// WBF: write ybf = bf16(dinv[r]*v) PANEL-MAJOR 32-wide. NOC: skip fp32 C write.
template <int K, int PRO, int EPI, int STATS, int WBF, int ABF, int NOC>
__global__ __launch_bounds__(256)
void mgemm_kernel(const void* __restrict__ Araw,
                  const ushort* __restrict__ Bhi, const ushort* __restrict__ Blo,
                  const float* __restrict__ bias,
                  const float* __restrict__ g, const float* __restrict__ bt,
                  const float* __restrict__ fsum, const float* __restrict__ fsq, float invn,
                  const float* __restrict__ y0, const float* __restrict__ dinv,
                  float* __restrict__ C, ushort* __restrict__ ybf,
                  float* __restrict__ ssum, float* __restrict__ ssq, int n) {
    constexpr int KC = 64;                // K-chunk in LDS: 128 x 64 x 2B x2 = 32 KB
    constexpr int NCC = KC / 16;          // MFMA sub-chunks per stage = 4
    __shared__ __align__(16) ushort Bh[128 * KC];
    __shared__ __align__(16) ushort Bl[128 * KC];
    __shared__ float scs[128], shs[128];
    __shared__ float csum[128], csq[128];
    const int tid = threadIdx.x;
    const int lane = tid & 63;
    const int w = tid >> 6;
    const int m = lane & 31;
    const int half = lane >> 5;
    const int rowbase = blockIdx.x * 128;
    const int grow = rowbase + w * 32 + m;
    const bool rok = grow < n;
    const size_t pstr = (size_t)n << 5;   // 32-wide panel stride in ushorts

    if (PRO == 1 && tid < K) {
        float mn = fsum[tid] * invn;
        float var = fmaxf(fsq[tid] * invn - mn * mn, 0.0f);
        float sc = g[tid] * rsqrtf(var + 1e-5f);
        scs[tid] = sc;
        shs[tid] = bt[tid] - mn * sc;
    }

    float16 acc[4];
#pragma unroll
    for (int t = 0; t < 4; ++t) acc[t] = (float16)(0.0f);

#pragma unroll
    for (int kc = 0; kc < K; kc += KC) {
        if (kc) __syncthreads();   // protect LDS reuse across chunks

        // --- stage B chunk (hi/lo), XOR-swizzled 16B groups: 128 rows x 8 groups ---
#pragma unroll
        for (int it = 0; it < 4; ++it) {
            int gi = it * 256 + tid;
            int nn = gi >> 3;
            int gg = gi & 7;
            int dst = nn * KC + ((gg ^ (nn & 7)) << 3);
            *(ushort8v*)&Bh[dst] = *(const ushort8v*)(Bhi + (size_t)nn * K + kc + (gg << 3));
            *(ushort8v*)&Bl[dst] = *(const ushort8v*)(Blo + (size_t)nn * K + kc + (gg << 3));
        }

        // --- preload A chunk to registers ---
        float4 aR[2 * NCC];
        short8 aB[NCC];
        if (ABF) {
#pragma unroll
            for (int cc = 0; cc < NCC; ++cc) {
                const int k0 = kc + cc * 16 + half * 8;
                const ushort* Ab = (const ushort*)Araw + (size_t)(k0 >> 5) * pstr
                                   + ((size_t)grow << 5) + (k0 & 31);
                aB[cc] = rok ? *(const short8*)(Ab) : (short8)(short)0;
            }
        } else {
            const float* A = (const float*)Araw + (size_t)grow * K;
#pragma unroll
            for (int cc = 0; cc < NCC; ++cc) {
                const int k0 = kc + cc * 16 + half * 8;
                aR[2 * cc]     = rok ? *(const float4*)(A + k0)     : make_float4(0.f, 0.f, 0.f, 0.f);
                aR[2 * cc + 1] = rok ? *(const float4*)(A + k0 + 4) : make_float4(0.f, 0.f, 0.f, 0.f);
            }
        }

        __syncthreads();

#pragma unroll
        for (int cc = 0; cc < NCC; ++cc) {
            short8 ah, al;
            if (ABF) {
                ah = aB[cc];
            } else {
                float av[8] = {aR[2 * cc].x,     aR[2 * cc].y,     aR[2 * cc].z,     aR[2 * cc].w,
                               aR[2 * cc + 1].x, aR[2 * cc + 1].y, aR[2 * cc + 1].z, aR[2 * cc + 1].w};
                if (PRO == 1) {
                    const int kb = kc + cc * 16 + half * 8;
#pragma unroll
                    for (int q = 0; q < 8; ++q)
                        av[q] = fmaxf(fmaf(av[q], scs[kb + q], shs[kb + q]), 0.f);
                }
#pragma unroll
                for (int q = 0; q < 8; ++q) {
                    ushort h = f2bf(av[q]);
                    ah[q] = (short)h;
                    al[q] = (short)f2bf(av[q] - bf2f(h));
                }
            }
            const int gg = 2 * cc + half;
#pragma unroll
            for (int t = 0; t < 4; ++t) {
                const int nn = t * 32 + m;
                const int bo = nn * KC + ((gg ^ (nn & 7)) << 3);
                short8 bh = *(const short8*)&Bh[bo];
                short8 bl = *(const short8*)&Bl[bo];
                acc[t] = __builtin_amdgcn_mfma_f32_32x32x16_bf16(ah, bh, acc[t], 0, 0, 0);
                acc[t] = __builtin_amdgcn_mfma_f32_32x32x16_bf16(ah, bl, acc[t], 0, 0, 0);
                if (!ABF)
                    acc[t] = __builtin_amdgcn_mfma_f32_32x32x16_bf16(al, bh, acc[t], 0, 0, 0);
            }
        }
    }

    // --- epilogue ---
    float lsum[4], lsq[4];
    if (STATS) {
#pragma unroll
        for (int t = 0; t < 4; ++t) { lsum[t] = 0.f; lsq[t] = 0.f; }
    }
#pragma unroll
    for (int t = 0; t < 4; ++t) {
        const int col = t * 32 + m;
        const float bv = bias ? bias[col] : 0.0f;
        const size_t wboff = WBF ? ((size_t)(col >> 5) * pstr + (col & 31)) : 0;
#pragma unroll
        for (int r = 0; r < 16; ++r) {
            int rowl = w * 32 + (r & 3) + 8 * (r >> 2) + 4 * half;
            int gr = rowbase + rowl;
            if (gr < n) {
                float v = acc[t][r] + bv;
                if (EPI == 1) v = 1.0f / (1.0f + __expf(-v));
                if (EPI == 2 || EPI == 3) {
                    float t0 = y0[(size_t)gr * H + col];
                    v *= (EPI == 2) ? t0 * t0 : t0;
                }
                if (!NOC) C[(size_t)gr * H + col] = v;
                if (WBF) ybf[wboff + ((size_t)gr << 5)] = f2bf(dinv[gr] * v);
                if (STATS) { lsum[t] += v; lsq[t] += v * v; }
            }
        }
    }
    if (STATS) {
        if (tid < 128) { csum[tid] = 0.f; csq[tid] = 0.f; }
        __syncthreads();
#pragma unroll
        for (int t = 0; t < 4; ++t) {
            atomicAdd(&csum[t * 32 + m], lsum[t]);
            atomicAdd(&csq[t * 32 + m], lsq[t]);
        }
        __syncthreads();
        if (tid < 128) {
            atomicAdd(&ssum[tid], csum[tid]);
            atomicAdd(&ssq[tid], csq[tid]);
        }
    }
}

// ---------------- batchnorm apply (in-block finalize) + relu + residual ----------------
__global__ void bn_relu_res_kernel(float* __restrict__ io, const float* __restrict__ res,
                                   const float* __restrict__ fsum, const float* __restrict__ fsq,
                                   const float* __restrict__ g, const float* __restrict__ bt,
                                   float invn, int total4) {
    __shared__ float scs[128], shs[128];
    int tid = threadIdx.x;
    if (tid < 128) {
        float mn = fsum[tid] * invn;
        float var = fmaxf(fsq[tid] * invn - mn * mn, 0.0f);
        float sc = g[tid] * rsqrtf(var + 1e-5f);
        scs[tid] = sc;
        shs[tid] = bt[tid] - mn * sc;
    }
    __syncthreads();
    int i = blockIdx.x * 256 + tid;
    if (i >= total4) return;
    float4 v = ((float4*)io)[i];
    int c = (i << 2) & 127;
    v.x = fmaxf(fmaf(v.x, scs[c],     shs[c]),     0.f);
    v.y = fmaxf(fmaf(v.y, scs[c + 1], shs[c + 1]), 0.f);
    v.z = fmaxf(fmaf(v.z, scs[c + 2], shs[c + 2]), 0.f);
    v.w = fmaxf(fmaf(v.w, scs[c + 3], shs[c + 3]), 0.f);
    if (res) {
        float4 r = ((const float4*)res)[i];
        v.x += r.x; v.y += r.y; v.z += r.z; v.w += r.w;
    }
    ((float4*)io)[i] = v;
}

} // namespace

extern "C" void kernel_launch(void* const* d_in, const int* in_sizes, int n_in,
                              void* d_out, int out_size, void* d_ws, size_t ws_size,
                              hipStream_t stream) {
    const float* x     = (const float*)d_in[0];
    const int*   ei    = (const int*)d_in[1];
    const float* W_in  = (const float*)d_in[2];
    const float* b_in  = (const float*)d_in[3];
    const float* g_in  = (const float*)d_in[4];
    const float* bt_in = (const float*)d_in[5];
    const float* Wf    = (const float*)d_in[6];
    const float* Wa    = (const float*)d_in[7];
    const float* g_nm  = (const float*)d_in[8];
    const float* bt_nm = (const float*)d_in[9];
    const float* W_o1  = (const float*)d_in[10];
    const float* b_o1  = (const float*)d_in[11];
    const float* g_o   = (const float*)d_in[12];
    const float* bt_o  = (const float*)d_in[13];
    const float* W_o2  = (const float*)d_in[14];
    const float* b_o2  = (const float*)d_in[15];
    float* out = (float*)d_out;

    const int N = in_sizes[0] / 64;
    const int E = in_sizes[1] / 2;

    char* wsp = (char*)d_ws;
    size_t off = 0;
    auto alloc = [&](size_t bytes) -> void* {
        void* p = wsp + off;
        off = (off + bytes + 255) & ~(size_t)255;
        return p;
    };
    int*    flag  = (int*)   alloc(4);
    float*  stats = (float*) alloc(4096);                // 4 slices of (ssum128|ssq128)
    ushort* win_h = (ushort*)alloc(64 * H * 2);
    ushort* win_l = (ushort*)alloc(64 * H * 2);
    ushort* w8_h  = (ushort*)alloc(8 * H * H * 2);
    ushort* w8_l  = (ushort*)alloc(8 * H * H * 2);
    int*    cnts  = (int*)   alloc((size_t)2 * N * 4);   // degi | cnt (one memset)
    int*    degi  = cnts;
    int*    cnt   = cnts + N;
    float*  dinv  = (float*) alloc((size_t)N * 4);
    ushort* csr   = (ushort*)alloc((size_t)N * 32 * 2);  // main table (deg<=32)
    ushort* csr2  = (ushort*)alloc((size_t)N * 32 * 2);  // spill (32<deg<=64)
    ushort* zb    = (ushort*)alloc((size_t)N * H * 2);   // panel-major z (dinv-scaled)
    ushort* tz    = (ushort*)alloc((size_t)N * H * 2);   // panel-major spmm output
    float*  b0    = (float*) alloc((size_t)N * H * 4);
    float*  b1    = (float*) alloc((size_t)N * H * 4);
    float*  b3    = (float*) alloc((size_t)N * H * 4);

    float* s0 = stats;
    float* s1 = stats + 256;
    float* s2 = stats + 512;
    float* s3 = stats + 768;

    const int TB = 256;
    const int gE = (E + TB - 1) / TB;
    const int gN = (N + TB - 1) / TB;
    const int gG = (N + 127) / 128;
    const int gS = ((N + 31) / 32) * 8;     // 8 blocks (4 panels x 2 row-halves) per 32 rows
    const int gV = (N * H / 4 + TB - 1) / TB;
    const float invn = 1.0f / (float)N;
    const size_t HH = (size_t)H * H;

    // --- graph preprocessing: one pass ---
    detect_kernel<<<1, TB, 0, stream>>>(ei, flag);
    hipMemsetAsync(cnts, 0, (size_t)2 * N * 4, stream);
    hipMemsetAsync(stats, 0, 4096, stream);
    build_kernel<<<gE, TB, 0, stream>>>(ei, flag, degi, cnt, csr, csr2, E);
    dinv_kernel<<<gN, TB, 0, stream>>>(degi, dinv, N);

    // --- weight split prep ---
    wprep_in_kernel<<<(64 * H) / 256, TB, 0, stream>>>(W_in, win_h, win_l);
    wprep8_kernel<<<(8 * H * H) / 256, TB, 0, stream>>>(Wf, Wa, W_o1, W_o2, w8_h, w8_l);

    // --- input encoder: h = relu(BN(x @ W_in + b_in)) -> b0 ---
    mgemm_kernel<64, 0, 0, 1, 0, 0, 0><<<gG, TB, 0, stream>>>(x, win_h, win_l, b_in,
        nullptr, nullptr, nullptr, nullptr, 0.f, nullptr, nullptr,
        b0, nullptr, s0, s0 + 128, N);
    bn_relu_res_kernel<<<gV, TB, 0, stream>>>(b0, nullptr, s0, s0 + 128, g_in, bt_in,
                                              invn, N * H / 4);

    // --- RWKP conv layers ---
    float* hb = b0;
    float* fb = b3;
    float* slayer[2] = {s1, s2};
    for (int l = 0; l < 3; ++l) {
        const ushort* wfh = w8_h + (size_t)l * HH;
        const ushort* wfl = w8_l + (size_t)l * HH;
        const ushort* wah = w8_h + (size_t)(3 + l) * HH;
        const ushort* wal = w8_l + (size_t)(3 + l) * HH;
        // y0 = sigmoid(h @ Wf_l) -> b1 (fp32) + zb (bf16 panel-major, dinv-scaled)
        mgemm_kernel<128, 0, 1, 0, 1, 0, 0><<<gG, TB, 0, stream>>>(hb, wfh, wfl, nullptr,
            nullptr, nullptr, nullptr, nullptr, 0.f, nullptr, dinv,
            b1, zb, nullptr, nullptr, N);
        // t = A*y0 -> tz (bf16 panel-major)
        spmm_kernel<<<gS, TB, 0, stream>>>(cnt, csr, csr2, dinv, zb, tz, N);
        // y1 = y0^2 * (t @ Wa_l) -> zb only (bf16 panel-major, dinv-scaled)
        mgemm_kernel<128, 0, 2, 0, 1, 1, 1><<<gG, TB, 0, stream>>>(tz, wah, wal, nullptr,
            nullptr, nullptr, nullptr, nullptr, 0.f, b1, dinv,
            nullptr, zb, nullptr, nullptr, N);
        // t = A*y1 -> tz (bf16 panel-major)
        spmm_kernel<<<gS, TB, 0, stream>>>(cnt, csr, csr2, dinv, zb, tz, N);
        // hc = y0 * (t @ Wa_l) -> fb (fp32)
        if (l < 2) {
            float* sl = slayer[l];
            mgemm_kernel<128, 0, 3, 1, 0, 1, 0><<<gG, TB, 0, stream>>>(tz, wah, wal, nullptr,
                nullptr, nullptr, nullptr, nullptr, 0.f, b1, nullptr,
                fb, nullptr, sl, sl + 128, N);
            bn_relu_res_kernel<<<gV, TB, 0, stream>>>(fb, hb, sl, sl + 128,
                g_nm + l * H, bt_nm + l * H, invn, N * H / 4);
            float* t = hb; hb = fb; fb = t;
        } else {
            mgemm_kernel<128, 0, 3, 0, 0, 1, 0><<<gG, TB, 0, stream>>>(tz, wah, wal, nullptr,
                nullptr, nullptr, nullptr, nullptr, 0.f, b1, nullptr,
                fb, nullptr, nullptr, nullptr, N);
            hb = fb;
        }
    }

    // --- output encoder ---
    mgemm_kernel<128, 0, 0, 1, 0, 0, 0><<<gG, TB, 0, stream>>>(hb, w8_h + 6 * HH, w8_l + 6 * HH,
        b_o1, nullptr, nullptr, nullptr, nullptr, 0.f, nullptr, nullptr,
        b1, nullptr, s3, s3 + 128, N);
    mgemm_kernel<128, 1, 0, 0, 0, 0, 0><<<gG, TB, 0, stream>>>(b1, w8_h + 7 * HH, w8_l + 7 * HH,
        b_o2, g_o, bt_o, s3, s3 + 128, invn, nullptr, nullptr,
        out, nullptr, nullptr, nullptr, N);
}